// Round 7
// baseline (1540.369 us; speedup 1.0000x reference)
//
#include <hip/hip_runtime.h>
#include <hip/hip_bf16.h>

// MultiSemanticSPR: B=4096, H=1024, S=7
// Round 6: identical to round 5 except the workspace-layout fix: `part` was
// offset by Pb's size in SHORTS/2 instead of FLOATS, aliasing the second half
// of Pb (loss partials corrupted p rows 2048+, p-GEMM writes corrupted
// partials). Now part = after_chunk + 14,680,064. Total = 45,117,456 floats
// = 180.47MB (tier-A proven in R3 via its 35MB-write fusion1 dispatch).

#define H 1024
#define SGS 7
#define BATCH 4096
#define BC 1024
#define EPS 1e-6f

typedef long long i64;
typedef __attribute__((ext_vector_type(8))) short short8;
typedef __attribute__((ext_vector_type(4))) float f32x4;

__device__ __forceinline__ unsigned short f2bf(float f) {
  __hip_bfloat16 h = __float2bfloat16(f);   // RNE
  return __builtin_bit_cast(unsigned short, h);
}
__device__ __forceinline__ float b2f(unsigned short u) {
  unsigned int x = ((unsigned int)u) << 16;
  return __builtin_bit_cast(float, x);
}
__device__ __forceinline__ short8 pack8(float4 a, float4 b) {
  short8 r;
  r[0] = (short)f2bf(a.x); r[1] = (short)f2bf(a.y);
  r[2] = (short)f2bf(a.z); r[3] = (short)f2bf(a.w);
  r[4] = (short)f2bf(b.x); r[5] = (short)f2bf(b.y);
  r[6] = (short)f2bf(b.z); r[7] = (short)f2bf(b.w);
  return r;
}

#define GL16(gp, lp)                                                        \
  __builtin_amdgcn_global_load_lds(                                         \
      (const __attribute__((address_space(1))) unsigned int*)(gp),          \
      (__attribute__((address_space(3))) unsigned int*)(lp), 16, 0, 0)

// ============ m97-style GEMM: A[M][K] @ Bt[N][K]^T (+bias)(+relu) ==========
// A bf16 (ABF16=1, global_load_lds) or fp32 (ABF16=0, reg-staged); Bt bf16.
// OM bit0 fp32 out, bit1 bf16 out. Tile 128x128, BK=32, 256 thr (4 waves,
// 64x64/wave, 4x4 frags of 16x16x32). LDS [128][32] bf16 linear, 16B slots
// XOR-swizzled: LDS slot sl at row r holds global k-slot sl^(r&3).
template <int ABF16, int OM>
__global__ __launch_bounds__(256) void ggemm_k(
    const void* __restrict__ Av, int lda, i64 sA,
    const unsigned short* __restrict__ Bt, int ldb, i64 sB,
    float* __restrict__ Cf, unsigned short* __restrict__ Cb, int ldc, i64 sC,
    const float* __restrict__ bias, i64 sBias, int K, int relu)
{
  __shared__ __align__(16) unsigned short As[128 * 32];
  __shared__ __align__(16) unsigned short Bs[128 * 32];

  const int tid  = threadIdx.x;
  const int lane = tid & 63;
  const int w    = tid >> 6;
  const int wr   = w >> 1, wc = w & 1;   // wave tile rows wr*64, cols wc*64

  const i64 row0 = (i64)blockIdx.y * 128;
  const i64 col0 = (i64)blockIdx.x * 128;

  const float* Af = (const float*)Av + (i64)blockIdx.z * sA;
  const unsigned short* Ab = (const unsigned short*)Av + (i64)blockIdx.z * sA;
  Bt += (i64)blockIdx.z * sB;
  if (OM & 1) Cf += (i64)blockIdx.z * sC;
  if (OM & 2) Cb += (i64)blockIdx.z * sC;
  const float* bi = bias ? bias + (i64)blockIdx.z * sBias : nullptr;

  // gload staging geometry (bf16 operands): wave w, call c in {0,1}:
  //   LDS rows w*32 + c*16 + (l>>2), 16B slot (l&3); global k-slot
  //   (l&3)^((l>>2)&3)  [slot-XOR swizzle, row&3 == (l>>2)&3]
  const int gr  = lane >> 2;
  const int gsl = (lane & 3) ^ (gr & 3);           // pre-swizzled global slot
  const i64 aRow0 = row0 + w * 32 + gr;            // + c*16
  const i64 bRow0 = col0 + w * 32 + gr;
  const unsigned short* ApB = Ab + aRow0 * (i64)lda + gsl * 8;
  const unsigned short* BpB = Bt + bRow0 * (i64)ldb + gsl * 8;
  unsigned short* AlB = &As[(w * 32) * 32];        // wave-uniform LDS bases
  unsigned short* BlB = &Bs[(w * 32) * 32];

  // fp32-A staging geometry: thread t -> row t>>1, 16 k-els at (t&1)*16
  const int arow = tid >> 1, aks = (tid & 1) * 2;  // 2 slots: aks, aks+1
  const float* ApF = Af + (row0 + arow) * (i64)lda + aks * 8;

  f32x4 acc[4][4];
#pragma unroll
  for (int i = 0; i < 4; ++i)
#pragma unroll
    for (int j = 0; j < 4; ++j) acc[i][j] = (f32x4){0.f, 0.f, 0.f, 0.f};

  const int kq = lane >> 4, lr = lane & 15;

  for (int k0 = 0; k0 < K; k0 += 32) {
    float4 fa0, fa1, fa2, fa3;
    if constexpr (!ABF16) {   // load before barrier (overlap prev compute)
      fa0 = *(const float4*)(ApF + k0);
      fa1 = *(const float4*)(ApF + k0 + 4);
      fa2 = *(const float4*)(ApF + k0 + 8);
      fa3 = *(const float4*)(ApF + k0 + 12);
    }
    __syncthreads();  // prior frag reads done before overwrite
    if constexpr (ABF16) {
      GL16(ApB + k0, AlB);
      GL16(ApB + k0 + (i64)16 * lda, AlB + 16 * 32);
    } else {
      *(short8*)(void*)&As[arow * 32 + (((aks)     ^ (arow & 3)) << 3)] = pack8(fa0, fa1);
      *(short8*)(void*)&As[arow * 32 + (((aks + 1) ^ (arow & 3)) << 3)] = pack8(fa2, fa3);
    }
    GL16(BpB + k0, BlB);
    GL16(BpB + k0 + (i64)16 * ldb, BlB + 16 * 32);
    __syncthreads();  // compiler drains vmcnt/lgkm before barrier

    short8 af[4], bf[4];
#pragma unroll
    for (int mf = 0; mf < 4; ++mf) {
      const int R = wr * 64 + mf * 16 + lr;
      af[mf] = *(const short8*)(const void*)&As[R * 32 + ((kq ^ (lr & 3)) << 3)];
    }
#pragma unroll
    for (int nf = 0; nf < 4; ++nf) {
      const int R = wc * 64 + nf * 16 + lr;
      bf[nf] = *(const short8*)(const void*)&Bs[R * 32 + ((kq ^ (lr & 3)) << 3)];
    }
#pragma unroll
    for (int mf = 0; mf < 4; ++mf)
#pragma unroll
      for (int nf = 0; nf < 4; ++nf)
        acc[mf][nf] = __builtin_amdgcn_mfma_f32_16x16x32_bf16(
            af[mf], bf[nf], acc[mf][nf], 0, 0, 0);
  }

  // epilogue: D col = lane&15, row = (lane>>4)*4 + reg  [verified r2-r4]
  const int cl = lane & 15, rg = lane >> 4;
#pragma unroll
  for (int nf = 0; nf < 4; ++nf) {
    const i64 col = col0 + wc * 64 + nf * 16 + cl;
    const float bv = bi ? bi[col] : 0.f;
#pragma unroll
    for (int mf = 0; mf < 4; ++mf) {
#pragma unroll
      for (int r = 0; r < 4; ++r) {
        const i64 row = row0 + wr * 64 + mf * 16 + rg * 4 + r;
        float v = acc[mf][nf][r] + bv;
        if (relu) v = fmaxf(v, 0.f);
        if (OM & 1) Cf[row * (i64)ldc + col] = v;
        if (OM & 2) Cb[row * (i64)ldc + col] = f2bf(v);
      }
    }
  }
}

// ====== R4 512-thr GEMM (kept for fusion1: A bf16, B fp32 row-major) =======
__device__ __forceinline__ int lidx40(int row, int slot) {
  return row * 40 + ((slot ^ ((row >> 2) & 3)) << 3);
}
template <int ABF16, int OM>
__global__ __launch_bounds__(512) void bgemm_k(
    const void* __restrict__ Av, int lda, i64 sA,
    const float* __restrict__ Bm, int ldb, i64 sB,
    float* __restrict__ Cf, unsigned short* __restrict__ Cb, int ldc, i64 sC,
    const float* __restrict__ bias, i64 sBias, int K, int relu)
{
  __shared__ __align__(16) unsigned short As[2][128 * 40];
  __shared__ __align__(16) unsigned short Bs[2][128 * 40];

  const int tid  = threadIdx.x;
  const int lane = tid & 63;
  const int w    = tid >> 6;
  const int wr   = w >> 1, wc = w & 1;

  const i64 row0 = (i64)blockIdx.y * 128;
  const i64 col0 = (i64)blockIdx.x * 128;

  const float* Af = (const float*)Av + (i64)blockIdx.z * sA;
  const unsigned short* Ab = (const unsigned short*)Av + (i64)blockIdx.z * sA;
  Bm += (i64)blockIdx.z * sB;
  if (OM & 1) Cf += (i64)blockIdx.z * sC;
  if (OM & 2) Cb += (i64)blockIdx.z * sC;
  const float* bi = bias ? bias + (i64)blockIdx.z * sBias : nullptr;

  const int arow = tid >> 2, akc = (tid & 3) * 8;
  const float* Ap = Af + (row0 + arow) * (i64)lda + akc;
  const unsigned short* Apb = Ab + (row0 + arow) * (i64)lda + akc;
  const int bcol = (tid & 31) * 4, bk = (tid >> 5) * 2;
  const float* Bp = Bm + (i64)bk * ldb + col0 + bcol;

  f32x4 acc[2][4];
#pragma unroll
  for (int i = 0; i < 2; ++i)
#pragma unroll
    for (int j = 0; j < 4; ++j) acc[i][j] = (f32x4){0.f, 0.f, 0.f, 0.f};

  float4 ra0, ra1; short8 ua; float4 rb0, rb1;
  if constexpr (ABF16) ua = *(const short8*)(const void*)(Apb);
  else { ra0 = *(const float4*)(Ap); ra1 = *(const float4*)(Ap + 4); }
  rb0 = *(const float4*)(Bp);
  rb1 = *(const float4*)(Bp + ldb);

  const int kSteps = K >> 5;
  int buf = 0;
  for (int s = 0; s < kSteps; ++s) {
    {
      short8 a8;
      if constexpr (ABF16) a8 = ua; else a8 = pack8(ra0, ra1);
      *(short8*)(void*)&As[buf][lidx40(arow, akc >> 3)] = a8;
      const int slot = bk >> 3, kin = bk & 7;
#pragma unroll
      for (int i = 0; i < 4; ++i) {
        const int row = bcol + i;
        ushort2 p2 = make_ushort2(f2bf(((const float*)&rb0)[i]),
                                  f2bf(((const float*)&rb1)[i]));
        *(ushort2*)(void*)&Bs[buf][row * 40 + ((slot ^ ((row >> 2) & 3)) << 3) + kin] = p2;
      }
    }
    if (s + 1 < kSteps) {
      const i64 k0 = (i64)(s + 1) * 32;
      if constexpr (ABF16) ua = *(const short8*)(const void*)(Apb + k0);
      else { ra0 = *(const float4*)(Ap + k0); ra1 = *(const float4*)(Ap + k0 + 4); }
      rb0 = *(const float4*)(Bp + k0 * (i64)ldb);
      rb1 = *(const float4*)(Bp + (k0 + 1) * (i64)ldb);
    }
    __syncthreads();
    const int kq = lane >> 4, lr = lane & 15;
    short8 af[2], bf[4];
#pragma unroll
    for (int mf = 0; mf < 2; ++mf)
      af[mf] = *(const short8*)(const void*)&As[buf][lidx40(wr * 32 + mf * 16 + lr, kq)];
#pragma unroll
    for (int nf = 0; nf < 4; ++nf)
      bf[nf] = *(const short8*)(const void*)&Bs[buf][lidx40(wc * 64 + nf * 16 + lr, kq)];
#pragma unroll
    for (int mf = 0; mf < 2; ++mf)
#pragma unroll
      for (int nf = 0; nf < 4; ++nf)
        acc[mf][nf] = __builtin_amdgcn_mfma_f32_16x16x32_bf16(
            af[mf], bf[nf], acc[mf][nf], 0, 0, 0);
    buf ^= 1;
  }

  const int cl = lane & 15, rg = lane >> 4;
#pragma unroll
  for (int nf = 0; nf < 4; ++nf) {
    const i64 col = col0 + wc * 64 + nf * 16 + cl;
    const float bv = bi ? bi[col] : 0.f;
#pragma unroll
    for (int mf = 0; mf < 2; ++mf) {
#pragma unroll
      for (int r = 0; r < 4; ++r) {
        const i64 row = row0 + wr * 32 + mf * 16 + rg * 4 + r;
        float v = acc[mf][nf][r] + bv;
        if (relu) v = fmaxf(v, 0.f);
        if (OM & 1) Cf[row * (i64)ldc + col] = v;
        if (OM & 2) Cb[row * (i64)ldc + col] = f2bf(v);
      }
    }
  }
}

// ---------- weight transpose+convert: in[K][N] fp32 -> out[N][K] bf16 ------
__global__ __launch_bounds__(256) void wtrans_k(
    const float* __restrict__ in, unsigned short* __restrict__ out,
    int Kd, int Nd, i64 sIn, i64 sOut)
{
  __shared__ float t[32][33];
  in  += (i64)blockIdx.z * sIn;
  out += (i64)blockIdx.z * sOut;
  const int n0 = blockIdx.x * 32, k0 = blockIdx.y * 32;
  const int tx = threadIdx.x & 31, ty = threadIdx.x >> 5;
#pragma unroll
  for (int i = 0; i < 4; ++i)
    t[ty + 8 * i][tx] = in[(i64)(k0 + ty + 8 * i) * Nd + n0 + tx];
  __syncthreads();
#pragma unroll
  for (int i = 0; i < 4; ++i)
    out[(i64)(n0 + ty + 8 * i) * Kd + k0 + tx] = f2bf(t[tx][ty + 8 * i]);
}

// ---------- fused LayerNorm + exact GELU + MGS: one WAVE per batch row -----
__global__ __launch_bounds__(256) void lnmgs_k(
    const unsigned short* __restrict__ X, const float* __restrict__ gamma,
    const float* __restrict__ beta, unsigned short* __restrict__ Hb)
{
  const int wv = threadIdx.x >> 6, l = threadIdx.x & 63;
  const i64 b = (i64)blockIdx.x * 4 + wv;
  const unsigned short* xr = X + b * (i64)(SGS * H);

  float g[16], be[16];
#pragma unroll
  for (int q = 0; q < 4; ++q) {
    float4 gv = *(const float4*)(gamma + l * 16 + q * 4);
    float4 bv = *(const float4*)(beta + l * 16 + q * 4);
    g[q*4+0] = gv.x; g[q*4+1] = gv.y; g[q*4+2] = gv.z; g[q*4+3] = gv.w;
    be[q*4+0] = bv.x; be[q*4+1] = bv.y; be[q*4+2] = bv.z; be[q*4+3] = bv.w;
  }

  float V[SGS][16];
#pragma unroll
  for (int s = 0; s < SGS; ++s) {
#pragma unroll
    for (int q = 0; q < 2; ++q) {
      short8 v8 = *(const short8*)(const void*)(xr + (i64)s * H + l * 16 + q * 8);
#pragma unroll
      for (int e = 0; e < 8; ++e)
        V[s][q * 8 + e] = b2f((unsigned short)v8[e]);
    }
    float s1 = 0.f, s2 = 0.f;
#pragma unroll
    for (int e = 0; e < 16; ++e) { s1 += V[s][e]; s2 += V[s][e] * V[s][e]; }
#pragma unroll
    for (int o = 1; o < 64; o <<= 1) { s1 += __shfl_xor(s1, o); s2 += __shfl_xor(s2, o); }
    const float mu = s1 * (1.f / H);
    const float var = s2 * (1.f / H) - mu * mu;
    const float rstd = rsqrtf(var + 1e-5f);
#pragma unroll
    for (int e = 0; e < 16; ++e) {
      float t = (V[s][e] - mu) * rstd * g[e] + be[e];
      V[s][e] = 0.5f * t * (1.f + erff(t * 0.70710678118654752f));
    }
  }

#pragma unroll
  for (int i = 0; i < SGS; ++i) {
#pragma unroll
    for (int j = 0; j < SGS; ++j) {
      if (j < i) {
        float cc = 0.f, dd = 0.f;
#pragma unroll
        for (int e = 0; e < 16; ++e) { cc += V[i][e] * V[j][e]; dd += V[j][e] * V[j][e]; }
#pragma unroll
        for (int o = 1; o < 64; o <<= 1) { cc += __shfl_xor(cc, o); dd += __shfl_xor(dd, o); }
        const float proj = (sqrtf(dd) > EPS) ? cc / dd : 0.f;
#pragma unroll
        for (int e = 0; e < 16; ++e) V[i][e] -= proj * V[j][e];
      }
    }
    float nn = 0.f;
#pragma unroll
    for (int e = 0; e < 16; ++e) nn += V[i][e] * V[i][e];
#pragma unroll
    for (int o = 1; o < 64; o <<= 1) nn += __shfl_xor(nn, o);
    const float n = sqrtf(nn);
    if (n > EPS) {   // fallback branch statistically unreachable here
      const float inv = 1.f / n;
#pragma unroll
      for (int e = 0; e < 16; ++e) V[i][e] *= inv;
    }
  }

  unsigned short* hr = Hb + b * (i64)(SGS * H) + l * 16;
#pragma unroll
  for (int s = 0; s < SGS; ++s) {
    short8 o;
#pragma unroll
    for (int e = 0; e < 8; ++e) o[e] = (short)f2bf(V[s][e]);
    *(short8*)(void*)(hr + (i64)s * H) = o;
#pragma unroll
    for (int e = 0; e < 8; ++e) o[e] = (short)f2bf(V[s][8 + e]);
    *(short8*)(void*)(hr + (i64)s * H + 8) = o;
  }
}

__device__ __forceinline__ float block_red(float v, float* scr) {
#pragma unroll
  for (int o = 32; o; o >>= 1) v += __shfl_down(v, o);
  int w = threadIdx.x >> 6;
  if ((threadIdx.x & 63) == 0) scr[w] = v;
  __syncthreads();
  v = scr[0] + scr[1] + scr[2] + scr[3];
  __syncthreads();
  return v;
}

// --------- loss: sum((p-h)^2), p bf16, h bf16 ------------------------------
__global__ __launch_bounds__(256) void loss_part_k(
    const unsigned short* __restrict__ p, const unsigned short* __restrict__ hb,
    float* __restrict__ part)
{
  __shared__ float scr[8];
  const i64 b = blockIdx.x;
  const int s = blockIdx.y;
  const i64 base = b * (i64)(SGS * H) + (i64)s * H;
  const int e = threadIdx.x * 4;
  ushort4 pv = *(const ushort4*)(p + base + e);
  ushort4 hv = *(const ushort4*)(hb + base + e);
  float d0 = b2f(pv.x) - b2f(hv.x), d1 = b2f(pv.y) - b2f(hv.y);
  float d2 = b2f(pv.z) - b2f(hv.z), d3 = b2f(pv.w) - b2f(hv.w);
  float acc = d0 * d0 + d1 * d1 + d2 * d2 + d3 * d3;
  acc = block_red(acc, scr);
  if (threadIdx.x == 0) part[(i64)s * BATCH + b] = acc;
}

__global__ __launch_bounds__(256) void loss_red_k(
    const float* __restrict__ part, float* __restrict__ losses)
{
  __shared__ float scr[8];
  const int s = blockIdx.x;
  float acc = 0.f;
  for (int e = threadIdx.x; e < BATCH; e += 256) acc += part[(i64)s * BATCH + e];
  acc = block_red(acc, scr);
  if (threadIdx.x == 0) losses[s] = acc / (float)((i64)BATCH * H);
}

__global__ void finalize_k(const float* __restrict__ losses,
                           const float* __restrict__ w, float* __restrict__ o)
{
  if (threadIdx.x == 0) {
    float t = 0.f;
#pragma unroll
    for (int s = 0; s < SGS; ++s) { float l = losses[s]; o[1 + s] = l; t += w[s] * l; }
    o[0] = t;
  }
}

// ---------------------------------------------------------------------------
extern "C" void kernel_launch(void* const* d_in, const int* in_sizes, int n_in,
                              void* d_out, int out_size, void* d_ws, size_t ws_size,
                              hipStream_t stream)
{
  (void)in_sizes; (void)n_in; (void)out_size; (void)ws_size;
  const float* sent    = (const float*)d_in[0];
  const float* decompW = (const float*)d_in[1];
  const float* ln_g    = (const float*)d_in[2];
  const float* ln_b    = (const float*)d_in[3];
  const float* pw1     = (const float*)d_in[4];
  const float* pb1     = (const float*)d_in[5];
  const float* pw2     = (const float*)d_in[6];
  const float* pb2     = (const float*)d_in[7];
  const float* qw1     = (const float*)d_in[8];
  const float* qb1     = (const float*)d_in[9];
  const float* qw2     = (const float*)d_in[10];
  const float* qb2     = (const float*)d_in[11];
  const float* fw1     = (const float*)d_in[12];
  const float* fb1     = (const float*)d_in[13];
  const float* fw2     = (const float*)d_in[14];
  const float* fb2     = (const float*)d_in[15];
  const float* semw    = (const float*)d_in[16];
  float* out = (float*)d_out;

  // ---- workspace layout: EXACTLY 45,117,456 floats (180.47MB) ----
  float* ws = (float*)d_ws;
  const i64 HHf = (i64)H * H / 2;                 // 1024x1024 bf16 el in floats
  unsigned short* pw1t = (unsigned short*)ws;     // [7][1024][1024] bf16 N-major
  unsigned short* pw2t = (unsigned short*)(ws + SGS * HHf);
  unsigned short* qw1t = (unsigned short*)(ws + 2 * SGS * HHf);
  unsigned short* qw2t = (unsigned short*)(ws + 3 * SGS * HHf);
  float* after_spr = ws + 4 * SGS * HHf;          // +14,680,064
  unsigned short* decompWt = (unsigned short*)after_spr;        // [7168][1024]
  float* after_dec = after_spr + 3670016;
  unsigned short* fw2t = (unsigned short*)after_dec;            // [1024][2048]
  float* after_fw2 = after_dec + 1048576;
  unsigned short* Xb = (unsigned short*)after_fw2;              // chunk [1024][7168]
  unsigned short* Hb = Xb + (i64)BC * SGS * H;
  unsigned short* Yb = Hb + (i64)BC * SGS * H;
  float* after_chunk = after_fw2 + 3 * 3670016;
  unsigned short* Pb = (unsigned short*)after_chunk;            // FULL [4096][7168]
  float* part   = after_chunk + 14680064;         // Pb = 14,680,064 FLOATS (fix)
  float* losses = part + (i64)SGS * BATCH;        // +16 spare
  unsigned short* T = Xb;                         // FULL t bf16 aliases Xb+Hb

  const dim3 blk(256);
  const dim3 g512(512);
  const i64 HH = (i64)H * H;

  // ---- one-time weight convert+transpose to bf16 N-major ----
  wtrans_k<<<dim3(32, 32, SGS), blk, 0, stream>>>(pw1, pw1t, H, H, HH, HH);
  wtrans_k<<<dim3(32, 32, SGS), blk, 0, stream>>>(pw2, pw2t, H, H, HH, HH);
  wtrans_k<<<dim3(32, 32, SGS), blk, 0, stream>>>(qw1, qw1t, H, H, HH, HH);
  wtrans_k<<<dim3(32, 32, SGS), blk, 0, stream>>>(qw2, qw2t, H, H, HH, HH);
  wtrans_k<<<dim3(224, 32, 1), blk, 0, stream>>>(decompW, decompWt, H, SGS * H, 0, 0);
  wtrans_k<<<dim3(32, 64, 1), blk, 0, stream>>>(fw2, fw2t, 2 * H, H, 0, 0);

  for (int c = 0; c < BATCH / BC; ++c) {
    const i64 r0 = (i64)c * BC;
    // 1) X = sent[chunk] @ decompW  (fp32 A, bf16 Bt) -> bf16
    ggemm_k<0, 2><<<dim3(56, BC / 128, 1), blk, 0, stream>>>(
        sent + r0 * H, H, 0, decompWt, H, 0, nullptr, Xb, SGS * H, 0,
        nullptr, 0, H, 0);
    // 2+3) Hb = MGS(gelu(LN(X)))
    lnmgs_k<<<dim3(BC / 4), blk, 0, stream>>>(Xb, ln_g, ln_b, Hb);
    // 4) z1 = relu(h @ pw1 + pb1) -> Yb
    ggemm_k<1, 2><<<dim3(8, BC / 128, SGS), blk, 0, stream>>>(
        Hb, SGS * H, H, pw1t, H, HH, nullptr, Yb, SGS * H, H, pb1, H, H, 1);
    // 5) z2 = z1 @ pw2 + pb2 -> Xb (dead)
    ggemm_k<1, 2><<<dim3(8, BC / 128, SGS), blk, 0, stream>>>(
        Yb, SGS * H, H, pw2t, H, HH, nullptr, Xb, SGS * H, H, pb2, H, H, 0);
    // 6) p1 = relu(z2 @ qw1 + qb1) -> Yb (dead)
    ggemm_k<1, 2><<<dim3(8, BC / 128, SGS), blk, 0, stream>>>(
        Xb, SGS * H, H, qw1t, H, HH, nullptr, Yb, SGS * H, H, qb1, H, H, 1);
    // 7) p = p1 @ qw2 + qb2 -> Pb[chunk]
    ggemm_k<1, 2><<<dim3(8, BC / 128, SGS), blk, 0, stream>>>(
        Yb, SGS * H, H, qw2t, H, HH, nullptr, Pb + r0 * SGS * H, SGS * H, H,
        qb2, H, H, 0);
    // 8) loss partials (bf16 p vs bf16 h)
    loss_part_k<<<dim3(BC, SGS), blk, 0, stream>>>(
        Pb + r0 * SGS * H, Hb, part + r0);
  }

  // 9) fusion full-batch. fusion1: R4 kernel (fw1 fp32, used once).
  //    T aliases Xb/Hb (dead after the loop).
  bgemm_k<1, 2><<<dim3(16, BATCH / 128, 1), g512, 0, stream>>>(
      Pb, SGS * H, 0, fw1, 2 * H, 0, nullptr, T, 2 * H, 0, fb1, 0, SGS * H, 1);
  //    fusion2: bf16 gload path
  ggemm_k<1, 1><<<dim3(8, BATCH / 128, 1), blk, 0, stream>>>(
      T, 2 * H, 0, fw2t, 2 * H, 0, out, nullptr, H, 0, fb2, 0, 2 * H, 0);

  // 10) reduce losses; write total + spr_losses after `final` in d_out
  loss_red_k<<<dim3(SGS), blk, 0, stream>>>(part, losses);
  finalize_k<<<dim3(1), dim3(64), 0, stream>>>(losses, semw, out + (i64)BATCH * H);
}

// Round 8
// 1433.522 us; speedup vs baseline: 1.0745x; 1.0745x over previous
//
#include <hip/hip_runtime.h>
#include <hip/hip_bf16.h>

// MultiSemanticSPR: B=4096, H=1024, S=7
// Round 7: restructure for GEMM shape efficiency.
//  - BC=2048 (2 chunks): SPR/decomp grids 448 -> 896 blocks (~3.5/CU).
//  - fusion1 on the gload ggemm path with pre-transposed bf16 fw1t
//    (bgemm_k deleted; its 8e7 bank conflicts go with it).
//  - One reusable W slab for the 4 SPR weights (re-transposed before each
//    use, ~7us each); z2 borrows the chunk's Pb rows; lnmgs in-place.
//  - Workspace total 45,117,456 floats == R6's proven 180.47MB exactly.

#define H 1024
#define SGS 7
#define BATCH 4096
#define BC 2048
#define EPS 1e-6f

typedef long long i64;
typedef __attribute__((ext_vector_type(8))) short short8;
typedef __attribute__((ext_vector_type(4))) float f32x4;

__device__ __forceinline__ unsigned short f2bf(float f) {
  __hip_bfloat16 h = __float2bfloat16(f);   // RNE
  return __builtin_bit_cast(unsigned short, h);
}
__device__ __forceinline__ float b2f(unsigned short u) {
  unsigned int x = ((unsigned int)u) << 16;
  return __builtin_bit_cast(float, x);
}
__device__ __forceinline__ short8 pack8(float4 a, float4 b) {
  short8 r;
  r[0] = (short)f2bf(a.x); r[1] = (short)f2bf(a.y);
  r[2] = (short)f2bf(a.z); r[3] = (short)f2bf(a.w);
  r[4] = (short)f2bf(b.x); r[5] = (short)f2bf(b.y);
  r[6] = (short)f2bf(b.z); r[7] = (short)f2bf(b.w);
  return r;
}

#define GL16(gp, lp)                                                        \
  __builtin_amdgcn_global_load_lds(                                         \
      (const __attribute__((address_space(1))) unsigned int*)(gp),          \
      (__attribute__((address_space(3))) unsigned int*)(lp), 16, 0, 0)

// ============ m97-style GEMM: A[M][K] @ Bt[N][K]^T (+bias)(+relu) ==========
// A bf16 (ABF16=1, global_load_lds) or fp32 (ABF16=0, reg-staged); Bt bf16
// N-major. OM bit0 fp32 out, bit1 bf16 out. Tile 128x128, BK=32, 256 thr
// (4 waves, 64x64/wave, 4x4 frags of 16x16x32). LDS [128][32] bf16 linear,
// 16B slots XOR-swizzled both-sides (pre-swizzled global source).
template <int ABF16, int OM>
__global__ __launch_bounds__(256) void ggemm_k(
    const void* __restrict__ Av, int lda, i64 sA,
    const unsigned short* __restrict__ Bt, int ldb, i64 sB,
    float* __restrict__ Cf, unsigned short* __restrict__ Cb, int ldc, i64 sC,
    const float* __restrict__ bias, i64 sBias, int K, int relu)
{
  __shared__ __align__(16) unsigned short As[128 * 32];
  __shared__ __align__(16) unsigned short Bs[128 * 32];

  const int tid  = threadIdx.x;
  const int lane = tid & 63;
  const int w    = tid >> 6;
  const int wr   = w >> 1, wc = w & 1;   // wave tile rows wr*64, cols wc*64

  const i64 row0 = (i64)blockIdx.y * 128;
  const i64 col0 = (i64)blockIdx.x * 128;

  const float* Af = (const float*)Av + (i64)blockIdx.z * sA;
  const unsigned short* Ab = (const unsigned short*)Av + (i64)blockIdx.z * sA;
  Bt += (i64)blockIdx.z * sB;
  if (OM & 1) Cf += (i64)blockIdx.z * sC;
  if (OM & 2) Cb += (i64)blockIdx.z * sC;
  const float* bi = bias ? bias + (i64)blockIdx.z * sBias : nullptr;

  // gload staging: wave w stages 32 LDS rows (2 calls x 16 rows); lane ->
  // row gr, 16B slot (l&3), global k-slot pre-swizzled gsl = (l&3)^(gr&3)
  const int gr  = lane >> 2;
  const int gsl = (lane & 3) ^ (gr & 3);
  const i64 aRow0 = row0 + w * 32 + gr;
  const i64 bRow0 = col0 + w * 32 + gr;
  const unsigned short* ApB = Ab + aRow0 * (i64)lda + gsl * 8;
  const unsigned short* BpB = Bt + bRow0 * (i64)ldb + gsl * 8;
  unsigned short* AlB = &As[(w * 32) * 32];
  unsigned short* BlB = &Bs[(w * 32) * 32];

  // fp32-A staging: thread t -> row t>>1, 16 k at (t&1)*16 (2 swizzled slots)
  const int arow = tid >> 1, aks = (tid & 1) * 2;
  const float* ApF = Af + (row0 + arow) * (i64)lda + aks * 8;

  f32x4 acc[4][4];
#pragma unroll
  for (int i = 0; i < 4; ++i)
#pragma unroll
    for (int j = 0; j < 4; ++j) acc[i][j] = (f32x4){0.f, 0.f, 0.f, 0.f};

  const int kq = lane >> 4, lr = lane & 15;

  for (int k0 = 0; k0 < K; k0 += 32) {
    float4 fa0, fa1, fa2, fa3;
    if constexpr (!ABF16) {   // load before barrier (overlaps prev MFMA)
      fa0 = *(const float4*)(ApF + k0);
      fa1 = *(const float4*)(ApF + k0 + 4);
      fa2 = *(const float4*)(ApF + k0 + 8);
      fa3 = *(const float4*)(ApF + k0 + 12);
    }
    __syncthreads();  // prior frag reads done before overwrite
    if constexpr (ABF16) {
      GL16(ApB + k0, AlB);
      GL16(ApB + k0 + (i64)16 * lda, AlB + 16 * 32);
    } else {
      *(short8*)(void*)&As[arow * 32 + (((aks)     ^ (arow & 3)) << 3)] = pack8(fa0, fa1);
      *(short8*)(void*)&As[arow * 32 + (((aks + 1) ^ (arow & 3)) << 3)] = pack8(fa2, fa3);
    }
    GL16(BpB + k0, BlB);
    GL16(BpB + k0 + (i64)16 * ldb, BlB + 16 * 32);
    __syncthreads();  // compiler drains vmcnt/lgkm before barrier

    short8 af[4], bf[4];
#pragma unroll
    for (int mf = 0; mf < 4; ++mf) {
      const int R = wr * 64 + mf * 16 + lr;
      af[mf] = *(const short8*)(const void*)&As[R * 32 + ((kq ^ (lr & 3)) << 3)];
    }
#pragma unroll
    for (int nf = 0; nf < 4; ++nf) {
      const int R = wc * 64 + nf * 16 + lr;
      bf[nf] = *(const short8*)(const void*)&Bs[R * 32 + ((kq ^ (lr & 3)) << 3)];
    }
#pragma unroll
    for (int mf = 0; mf < 4; ++mf)
#pragma unroll
      for (int nf = 0; nf < 4; ++nf)
        acc[mf][nf] = __builtin_amdgcn_mfma_f32_16x16x32_bf16(
            af[mf], bf[nf], acc[mf][nf], 0, 0, 0);
  }

  // epilogue: D col = lane&15, row = (lane>>4)*4 + reg  [verified r2-r6]
  const int cl = lane & 15, rg = lane >> 4;
#pragma unroll
  for (int nf = 0; nf < 4; ++nf) {
    const i64 col = col0 + wc * 64 + nf * 16 + cl;
    const float bv = bi ? bi[col] : 0.f;
#pragma unroll
    for (int mf = 0; mf < 4; ++mf) {
#pragma unroll
      for (int r = 0; r < 4; ++r) {
        const i64 row = row0 + wr * 64 + mf * 16 + rg * 4 + r;
        float v = acc[mf][nf][r] + bv;
        if (relu) v = fmaxf(v, 0.f);
        if (OM & 1) Cf[row * (i64)ldc + col] = v;
        if (OM & 2) Cb[row * (i64)ldc + col] = f2bf(v);
      }
    }
  }
}

// ---------- weight transpose+convert: in[K][N] fp32 -> out[N][K] bf16 ------
__global__ __launch_bounds__(256) void wtrans_k(
    const float* __restrict__ in, unsigned short* __restrict__ out,
    int Kd, int Nd, i64 sIn, i64 sOut)
{
  __shared__ float t[32][33];
  in  += (i64)blockIdx.z * sIn;
  out += (i64)blockIdx.z * sOut;
  const int n0 = blockIdx.x * 32, k0 = blockIdx.y * 32;
  const int tx = threadIdx.x & 31, ty = threadIdx.x >> 5;
#pragma unroll
  for (int i = 0; i < 4; ++i)
    t[ty + 8 * i][tx] = in[(i64)(k0 + ty + 8 * i) * Nd + n0 + tx];
  __syncthreads();
#pragma unroll
  for (int i = 0; i < 4; ++i)
    out[(i64)(n0 + ty + 8 * i) * Kd + k0 + tx] = f2bf(t[tx][ty + 8 * i]);
}

// ---------- fused LayerNorm + exact GELU + MGS: one WAVE per batch row -----
// In-place safe: each wave owns its row; reads all before writing.
__global__ __launch_bounds__(256) void lnmgs_k(
    const unsigned short* __restrict__ X, const float* __restrict__ gamma,
    const float* __restrict__ beta, unsigned short* __restrict__ Hb)
{
  const int wv = threadIdx.x >> 6, l = threadIdx.x & 63;
  const i64 b = (i64)blockIdx.x * 4 + wv;
  const unsigned short* xr = X + b * (i64)(SGS * H);

  float g[16], be[16];
#pragma unroll
  for (int q = 0; q < 4; ++q) {
    float4 gv = *(const float4*)(gamma + l * 16 + q * 4);
    float4 bv = *(const float4*)(beta + l * 16 + q * 4);
    g[q*4+0] = gv.x; g[q*4+1] = gv.y; g[q*4+2] = gv.z; g[q*4+3] = gv.w;
    be[q*4+0] = bv.x; be[q*4+1] = bv.y; be[q*4+2] = bv.z; be[q*4+3] = bv.w;
  }

  float V[SGS][16];
#pragma unroll
  for (int s = 0; s < SGS; ++s) {
#pragma unroll
    for (int q = 0; q < 2; ++q) {
      short8 v8 = *(const short8*)(const void*)(xr + (i64)s * H + l * 16 + q * 8);
#pragma unroll
      for (int e = 0; e < 8; ++e)
        V[s][q * 8 + e] = b2f((unsigned short)v8[e]);
    }
    float s1 = 0.f, s2 = 0.f;
#pragma unroll
    for (int e = 0; e < 16; ++e) { s1 += V[s][e]; s2 += V[s][e] * V[s][e]; }
#pragma unroll
    for (int o = 1; o < 64; o <<= 1) { s1 += __shfl_xor(s1, o); s2 += __shfl_xor(s2, o); }
    const float mu = s1 * (1.f / H);
    const float var = s2 * (1.f / H) - mu * mu;
    const float rstd = rsqrtf(var + 1e-5f);
#pragma unroll
    for (int e = 0; e < 16; ++e) {
      float t = (V[s][e] - mu) * rstd * g[e] + be[e];
      V[s][e] = 0.5f * t * (1.f + erff(t * 0.70710678118654752f));
    }
  }

#pragma unroll
  for (int i = 0; i < SGS; ++i) {
#pragma unroll
    for (int j = 0; j < SGS; ++j) {
      if (j < i) {
        float cc = 0.f, dd = 0.f;
#pragma unroll
        for (int e = 0; e < 16; ++e) { cc += V[i][e] * V[j][e]; dd += V[j][e] * V[j][e]; }
#pragma unroll
        for (int o = 1; o < 64; o <<= 1) { cc += __shfl_xor(cc, o); dd += __shfl_xor(dd, o); }
        const float proj = (sqrtf(dd) > EPS) ? cc / dd : 0.f;
#pragma unroll
        for (int e = 0; e < 16; ++e) V[i][e] -= proj * V[j][e];
      }
    }
    float nn = 0.f;
#pragma unroll
    for (int e = 0; e < 16; ++e) nn += V[i][e] * V[i][e];
#pragma unroll
    for (int o = 1; o < 64; o <<= 1) nn += __shfl_xor(nn, o);
    const float n = sqrtf(nn);
    if (n > EPS) {   // fallback branch statistically unreachable here
      const float inv = 1.f / n;
#pragma unroll
      for (int e = 0; e < 16; ++e) V[i][e] *= inv;
    }
  }

  unsigned short* hr = Hb + b * (i64)(SGS * H) + l * 16;
#pragma unroll
  for (int s = 0; s < SGS; ++s) {
    short8 o;
#pragma unroll
    for (int e = 0; e < 8; ++e) o[e] = (short)f2bf(V[s][e]);
    *(short8*)(void*)(hr + (i64)s * H) = o;
#pragma unroll
    for (int e = 0; e < 8; ++e) o[e] = (short)f2bf(V[s][8 + e]);
    *(short8*)(void*)(hr + (i64)s * H + 8) = o;
  }
}

__device__ __forceinline__ float block_red(float v, float* scr) {
#pragma unroll
  for (int o = 32; o; o >>= 1) v += __shfl_down(v, o);
  int w = threadIdx.x >> 6;
  if ((threadIdx.x & 63) == 0) scr[w] = v;
  __syncthreads();
  v = scr[0] + scr[1] + scr[2] + scr[3];
  __syncthreads();
  return v;
}

// --------- loss: sum((p-h)^2), p bf16, h bf16 ------------------------------
__global__ __launch_bounds__(256) void loss_part_k(
    const unsigned short* __restrict__ p, const unsigned short* __restrict__ hb,
    float* __restrict__ part)  // part pre-offset by chunk row0
{
  __shared__ float scr[8];
  const i64 b = blockIdx.x;
  const int s = blockIdx.y;
  const i64 base = b * (i64)(SGS * H) + (i64)s * H;
  const int e = threadIdx.x * 4;
  ushort4 pv = *(const ushort4*)(p + base + e);
  ushort4 hv = *(const ushort4*)(hb + base + e);
  float d0 = b2f(pv.x) - b2f(hv.x), d1 = b2f(pv.y) - b2f(hv.y);
  float d2 = b2f(pv.z) - b2f(hv.z), d3 = b2f(pv.w) - b2f(hv.w);
  float acc = d0 * d0 + d1 * d1 + d2 * d2 + d3 * d3;
  acc = block_red(acc, scr);
  if (threadIdx.x == 0) part[(i64)s * BATCH + b] = acc;
}

__global__ __launch_bounds__(256) void loss_red_k(
    const float* __restrict__ part, float* __restrict__ losses)
{
  __shared__ float scr[8];
  const int s = blockIdx.x;
  float acc = 0.f;
  for (int e = threadIdx.x; e < BATCH; e += 256) acc += part[(i64)s * BATCH + e];
  acc = block_red(acc, scr);
  if (threadIdx.x == 0) losses[s] = acc / (float)((i64)BATCH * H);
}

__global__ void finalize_k(const float* __restrict__ losses,
                           const float* __restrict__ w, float* __restrict__ o)
{
  if (threadIdx.x == 0) {
    float t = 0.f;
#pragma unroll
    for (int s = 0; s < SGS; ++s) { float l = losses[s]; o[1 + s] = l; t += w[s] * l; }
    o[0] = t;
  }
}

// ---------------------------------------------------------------------------
extern "C" void kernel_launch(void* const* d_in, const int* in_sizes, int n_in,
                              void* d_out, int out_size, void* d_ws, size_t ws_size,
                              hipStream_t stream)
{
  (void)in_sizes; (void)n_in; (void)out_size; (void)ws_size;
  const float* sent    = (const float*)d_in[0];
  const float* decompW = (const float*)d_in[1];
  const float* ln_g    = (const float*)d_in[2];
  const float* ln_b    = (const float*)d_in[3];
  const float* pw1     = (const float*)d_in[4];
  const float* pb1     = (const float*)d_in[5];
  const float* pw2     = (const float*)d_in[6];
  const float* pb2     = (const float*)d_in[7];
  const float* qw1     = (const float*)d_in[8];
  const float* qb1     = (const float*)d_in[9];
  const float* qw2     = (const float*)d_in[10];
  const float* qb2     = (const float*)d_in[11];
  const float* fw1     = (const float*)d_in[12];
  const float* fb1     = (const float*)d_in[13];
  const float* fw2     = (const float*)d_in[14];
  const float* fb2     = (const float*)d_in[15];
  const float* semw    = (const float*)d_in[16];
  float* out = (float*)d_out;

  // ---- workspace (floats), total 45,117,456 == R6's proven 180.47MB ----
  float* ws = (float*)d_ws;
  unsigned short* W        = (unsigned short*)(ws);             // [7][1024][1024] (reused)
  unsigned short* decompWt = (unsigned short*)(ws + 3670016);   // [7168][1024]
  unsigned short* fw1t     = (unsigned short*)(ws + 7340032);   // [2048][7168]
  unsigned short* fw2t     = (unsigned short*)(ws + 14680064);  // [1024][2048]
  unsigned short* XH       = (unsigned short*)(ws + 15728640);  // chunk [2048][7168]
  unsigned short* Y        = (unsigned short*)(ws + 23068672);  // chunk [2048][7168]
  unsigned short* Pb       = (unsigned short*)(ws + 30408704);  // FULL [4096][7168]
  float* part   = ws + 45088768;                                // [7][4096]
  float* losses = part + (i64)SGS * BATCH;
  unsigned short* T = Y;                                        // [4096][2048] fits in Y

  const dim3 blk(256);
  const i64 HH = (i64)H * H;
  const i64 SH = (i64)SGS * H;

  // ---- one-time transposes ----
  wtrans_k<<<dim3(224, 32, 1), blk, 0, stream>>>(decompW, decompWt, H, SGS * H, 0, 0);
  wtrans_k<<<dim3(64, 224, 1), blk, 0, stream>>>(fw1, fw1t, SGS * H, 2 * H, 0, 0);
  wtrans_k<<<dim3(32, 64, 1), blk, 0, stream>>>(fw2, fw2t, 2 * H, H, 0, 0);

  for (int c = 0; c < BATCH / BC; ++c) {
    const i64 r0 = (i64)c * BC;
    unsigned short* Pc = Pb + r0 * SH;   // this chunk's rows of full P
    // 1) X = sent[chunk] @ decompW  (fp32 A, bf16 Bt) -> bf16, 896 blocks
    ggemm_k<0, 2><<<dim3(56, BC / 128, 1), blk, 0, stream>>>(
        sent + r0 * H, H, 0, decompWt, H, 0, nullptr, XH, SGS * H, 0,
        nullptr, 0, H, 0);
    // 2+3) H = MGS(gelu(LN(X))), in place
    lnmgs_k<<<dim3(BC / 4), blk, 0, stream>>>(XH, ln_g, ln_b, XH);
    // 4) z1 = relu(h @ pw1 + pb1) -> Y          [W <- pw1^T]
    wtrans_k<<<dim3(32, 32, SGS), blk, 0, stream>>>(pw1, W, H, H, HH, HH);
    ggemm_k<1, 2><<<dim3(8, BC / 128, SGS), blk, 0, stream>>>(
        XH, SH, H, W, H, HH, nullptr, Y, SH, H, pb1, H, H, 1);
    // 5) z2 = z1 @ pw2 + pb2 -> Pc (borrowed)   [W <- pw2^T]
    wtrans_k<<<dim3(32, 32, SGS), blk, 0, stream>>>(pw2, W, H, H, HH, HH);
    ggemm_k<1, 2><<<dim3(8, BC / 128, SGS), blk, 0, stream>>>(
        Y, SH, H, W, H, HH, nullptr, Pc, SH, H, pb2, H, H, 0);
    // 6) p1 = relu(z2 @ qw1 + qb1) -> Y         [W <- qw1^T]
    wtrans_k<<<dim3(32, 32, SGS), blk, 0, stream>>>(qw1, W, H, H, HH, HH);
    ggemm_k<1, 2><<<dim3(8, BC / 128, SGS), blk, 0, stream>>>(
        Pc, SH, H, W, H, HH, nullptr, Y, SH, H, qb1, H, H, 1);
    // 7) p = p1 @ qw2 + qb2 -> Pc               [W <- qw2^T]
    wtrans_k<<<dim3(32, 32, SGS), blk, 0, stream>>>(qw2, W, H, H, HH, HH);
    ggemm_k<1, 2><<<dim3(8, BC / 128, SGS), blk, 0, stream>>>(
        Y, SH, H, W, H, HH, nullptr, Pc, SH, H, qb2, H, H, 0);
    // 8) loss partials (bf16 p vs bf16 h)
    loss_part_k<<<dim3(BC, SGS), blk, 0, stream>>>(Pc, XH, part + r0);
  }

  // 9) fusion full-batch on the gload path (K=7168, 512 blocks):
  //    T = relu(Pb @ fw1t + fb1) -> Y (bf16 4096x2048)
  ggemm_k<1, 2><<<dim3(16, BATCH / 128, 1), blk, 0, stream>>>(
      Pb, SH, 0, fw1t, SGS * H, 0, nullptr, T, 2 * H, 0, fb1, 0, SGS * H, 1);
  //    final = T @ fw2t + fb2 -> out (fp32)
  ggemm_k<1, 1><<<dim3(8, BATCH / 128, 1), blk, 0, stream>>>(
      T, 2 * H, 0, fw2t, 2 * H, 0, out, nullptr, H, 0, fb2, 0, 2 * H, 0);

  // 10) reduce losses; write total + spr_losses after `final` in d_out
  loss_red_k<<<dim3(SGS), blk, 0, stream>>>(part, losses);
  finalize_k<<<dim3(1), dim3(64), 0, stream>>>(losses, semw, out + (i64)BATCH * H);
}

// Round 9
// 1087.001 us; speedup vs baseline: 1.4171x; 1.3188x over previous
//
#include <hip/hip_runtime.h>
#include <hip/hip_bf16.h>

// MultiSemanticSPR: B=4096, H=1024, S=7
// Round 8:
//  (1) Bijective XCD-aware blockIdx swizzle (m204) in ggemm_k -> blocks that
//      share an A panel land on one XCD's L2; kills the 8x A re-fetch.
//  (2) Workspace-tiered restructure: if ws >= 190.96MB, stage-major
//      FULL-BATCH pipeline (3 x 58.7MB slabs + 14.7MB W slab; decompWt
//      aliases Pb, fw1t/fw2t/T alias U1 after H dies). All SPR GEMMs at
//      M=4096 (1792 blocks). Else: proven R7 layout (180.47MB), swizzled.

#define H 1024
#define SGS 7
#define BATCH 4096
#define EPS 1e-6f

typedef long long i64;
typedef __attribute__((ext_vector_type(8))) short short8;
typedef __attribute__((ext_vector_type(4))) float f32x4;

__device__ __forceinline__ unsigned short f2bf(float f) {
  __hip_bfloat16 h = __float2bfloat16(f);   // RNE
  return __builtin_bit_cast(unsigned short, h);
}
__device__ __forceinline__ float b2f(unsigned short u) {
  unsigned int x = ((unsigned int)u) << 16;
  return __builtin_bit_cast(float, x);
}
__device__ __forceinline__ short8 pack8(float4 a, float4 b) {
  short8 r;
  r[0] = (short)f2bf(a.x); r[1] = (short)f2bf(a.y);
  r[2] = (short)f2bf(a.z); r[3] = (short)f2bf(a.w);
  r[4] = (short)f2bf(b.x); r[5] = (short)f2bf(b.y);
  r[6] = (short)f2bf(b.z); r[7] = (short)f2bf(b.w);
  return r;
}

#define GL16(gp, lp)                                                        \
  __builtin_amdgcn_global_load_lds(                                         \
      (const __attribute__((address_space(1))) unsigned int*)(gp),          \
      (__attribute__((address_space(3))) unsigned int*)(lp), 16, 0, 0)

// Bijective XCD swizzle (m204): XCD (= orig%8) gets a contiguous chunk of
// the decoded index space; x decoded fastest so same-A-panel blocks cluster.
__device__ __forceinline__ void xcd_swz(int& bx, int& by, int& bz) {
  const int gx = gridDim.x, gy = gridDim.y;
  const int nwg = gx * gy * (int)gridDim.z;
  const int orig = blockIdx.x + gx * (blockIdx.y + gy * blockIdx.z);
  const int q = nwg >> 3, r = nwg & 7;
  const int xcd = orig & 7, idx = orig >> 3;
  const int nw = (xcd < r ? xcd * (q + 1) : r * (q + 1) + (xcd - r) * q) + idx;
  bx = nw % gx;
  const int t = nw / gx;
  by = t % gy;
  bz = t / gy;
}

// ============ m97-style GEMM: A[M][K] @ Bt[N][K]^T (+bias)(+relu) ==========
// A bf16 (ABF16=1, global_load_lds) or fp32 (ABF16=0, reg-staged); Bt bf16
// N-major. OM bit0 fp32 out, bit1 bf16 out. Tile 128x128, BK=32, 256 thr
// (4 waves, 64x64/wave, 4x4 frags of 16x16x32). LDS [128][32] bf16 linear,
// 16B slots XOR-swizzled both-sides (pre-swizzled global source).
template <int ABF16, int OM>
__global__ __launch_bounds__(256) void ggemm_k(
    const void* __restrict__ Av, int lda, i64 sA,
    const unsigned short* __restrict__ Bt, int ldb, i64 sB,
    float* __restrict__ Cf, unsigned short* __restrict__ Cb, int ldc, i64 sC,
    const float* __restrict__ bias, i64 sBias, int K, int relu)
{
  __shared__ __align__(16) unsigned short As[128 * 32];
  __shared__ __align__(16) unsigned short Bs[128 * 32];

  int bx, by, bz;
  xcd_swz(bx, by, bz);

  const int tid  = threadIdx.x;
  const int lane = tid & 63;
  const int w    = tid >> 6;
  const int wr   = w >> 1, wc = w & 1;   // wave tile rows wr*64, cols wc*64

  const i64 row0 = (i64)by * 128;
  const i64 col0 = (i64)bx * 128;

  const float* Af = (const float*)Av + (i64)bz * sA;
  const unsigned short* Ab = (const unsigned short*)Av + (i64)bz * sA;
  Bt += (i64)bz * sB;
  if (OM & 1) Cf += (i64)bz * sC;
  if (OM & 2) Cb += (i64)bz * sC;
  const float* bi = bias ? bias + (i64)bz * sBias : nullptr;

  // gload staging: wave w stages 32 LDS rows (2 calls x 16 rows); lane ->
  // row gr, 16B slot (l&3), global k-slot pre-swizzled gsl = (l&3)^(gr&3)
  const int gr  = lane >> 2;
  const int gsl = (lane & 3) ^ (gr & 3);
  const i64 aRow0 = row0 + w * 32 + gr;
  const i64 bRow0 = col0 + w * 32 + gr;
  const unsigned short* ApB = Ab + aRow0 * (i64)lda + gsl * 8;
  const unsigned short* BpB = Bt + bRow0 * (i64)ldb + gsl * 8;
  unsigned short* AlB = &As[(w * 32) * 32];
  unsigned short* BlB = &Bs[(w * 32) * 32];

  // fp32-A staging: thread t -> row t>>1, 16 k at (t&1)*16 (2 swizzled slots)
  const int arow = tid >> 1, aks = (tid & 1) * 2;
  const float* ApF = Af + (row0 + arow) * (i64)lda + aks * 8;

  f32x4 acc[4][4];
#pragma unroll
  for (int i = 0; i < 4; ++i)
#pragma unroll
    for (int j = 0; j < 4; ++j) acc[i][j] = (f32x4){0.f, 0.f, 0.f, 0.f};

  const int kq = lane >> 4, lr = lane & 15;

  for (int k0 = 0; k0 < K; k0 += 32) {
    float4 fa0, fa1, fa2, fa3;
    if constexpr (!ABF16) {   // load before barrier (overlaps prev MFMA)
      fa0 = *(const float4*)(ApF + k0);
      fa1 = *(const float4*)(ApF + k0 + 4);
      fa2 = *(const float4*)(ApF + k0 + 8);
      fa3 = *(const float4*)(ApF + k0 + 12);
    }
    __syncthreads();  // prior frag reads done before overwrite
    if constexpr (ABF16) {
      GL16(ApB + k0, AlB);
      GL16(ApB + k0 + (i64)16 * lda, AlB + 16 * 32);
    } else {
      *(short8*)(void*)&As[arow * 32 + (((aks)     ^ (arow & 3)) << 3)] = pack8(fa0, fa1);
      *(short8*)(void*)&As[arow * 32 + (((aks + 1) ^ (arow & 3)) << 3)] = pack8(fa2, fa3);
    }
    GL16(BpB + k0, BlB);
    GL16(BpB + k0 + (i64)16 * ldb, BlB + 16 * 32);
    __syncthreads();  // compiler drains vmcnt/lgkm before barrier

    short8 af[4], bf[4];
#pragma unroll
    for (int mf = 0; mf < 4; ++mf) {
      const int R = wr * 64 + mf * 16 + lr;
      af[mf] = *(const short8*)(const void*)&As[R * 32 + ((kq ^ (lr & 3)) << 3)];
    }
#pragma unroll
    for (int nf = 0; nf < 4; ++nf) {
      const int R = wc * 64 + nf * 16 + lr;
      bf[nf] = *(const short8*)(const void*)&Bs[R * 32 + ((kq ^ (lr & 3)) << 3)];
    }
#pragma unroll
    for (int mf = 0; mf < 4; ++mf)
#pragma unroll
      for (int nf = 0; nf < 4; ++nf)
        acc[mf][nf] = __builtin_amdgcn_mfma_f32_16x16x32_bf16(
            af[mf], bf[nf], acc[mf][nf], 0, 0, 0);
  }

  // epilogue: D col = lane&15, row = (lane>>4)*4 + reg  [verified r2-r7]
  const int cl = lane & 15, rg = lane >> 4;
#pragma unroll
  for (int nf = 0; nf < 4; ++nf) {
    const i64 col = col0 + wc * 64 + nf * 16 + cl;
    const float bv = bi ? bi[col] : 0.f;
#pragma unroll
    for (int mf = 0; mf < 4; ++mf) {
#pragma unroll
      for (int r = 0; r < 4; ++r) {
        const i64 row = row0 + wr * 64 + mf * 16 + rg * 4 + r;
        float v = acc[mf][nf][r] + bv;
        if (relu) v = fmaxf(v, 0.f);
        if (OM & 1) Cf[row * (i64)ldc + col] = v;
        if (OM & 2) Cb[row * (i64)ldc + col] = f2bf(v);
      }
    }
  }
}

// ---------- weight transpose+convert: in[K][N] fp32 -> out[N][K] bf16 ------
__global__ __launch_bounds__(256) void wtrans_k(
    const float* __restrict__ in, unsigned short* __restrict__ out,
    int Kd, int Nd, i64 sIn, i64 sOut)
{
  __shared__ float t[32][33];
  in  += (i64)blockIdx.z * sIn;
  out += (i64)blockIdx.z * sOut;
  const int n0 = blockIdx.x * 32, k0 = blockIdx.y * 32;
  const int tx = threadIdx.x & 31, ty = threadIdx.x >> 5;
#pragma unroll
  for (int i = 0; i < 4; ++i)
    t[ty + 8 * i][tx] = in[(i64)(k0 + ty + 8 * i) * Nd + n0 + tx];
  __syncthreads();
#pragma unroll
  for (int i = 0; i < 4; ++i)
    out[(i64)(n0 + ty + 8 * i) * Kd + k0 + tx] = f2bf(t[tx][ty + 8 * i]);
}

// ---------- fused LayerNorm + exact GELU + MGS: one WAVE per batch row -----
// In-place safe: each wave owns its row; reads all before writing.
__global__ __launch_bounds__(256) void lnmgs_k(
    const unsigned short* __restrict__ X, const float* __restrict__ gamma,
    const float* __restrict__ beta, unsigned short* __restrict__ Hb)
{
  const int wv = threadIdx.x >> 6, l = threadIdx.x & 63;
  const i64 b = (i64)blockIdx.x * 4 + wv;
  const unsigned short* xr = X + b * (i64)(SGS * H);

  float g[16], be[16];
#pragma unroll
  for (int q = 0; q < 4; ++q) {
    float4 gv = *(const float4*)(gamma + l * 16 + q * 4);
    float4 bv = *(const float4*)(beta + l * 16 + q * 4);
    g[q*4+0] = gv.x; g[q*4+1] = gv.y; g[q*4+2] = gv.z; g[q*4+3] = gv.w;
    be[q*4+0] = bv.x; be[q*4+1] = bv.y; be[q*4+2] = bv.z; be[q*4+3] = bv.w;
  }

  float V[SGS][16];
#pragma unroll
  for (int s = 0; s < SGS; ++s) {
#pragma unroll
    for (int q = 0; q < 2; ++q) {
      short8 v8 = *(const short8*)(const void*)(xr + (i64)s * H + l * 16 + q * 8);
#pragma unroll
      for (int e = 0; e < 8; ++e)
        V[s][q * 8 + e] = b2f((unsigned short)v8[e]);
    }
    float s1 = 0.f, s2 = 0.f;
#pragma unroll
    for (int e = 0; e < 16; ++e) { s1 += V[s][e]; s2 += V[s][e] * V[s][e]; }
#pragma unroll
    for (int o = 1; o < 64; o <<= 1) { s1 += __shfl_xor(s1, o); s2 += __shfl_xor(s2, o); }
    const float mu = s1 * (1.f / H);
    const float var = s2 * (1.f / H) - mu * mu;
    const float rstd = rsqrtf(var + 1e-5f);
#pragma unroll
    for (int e = 0; e < 16; ++e) {
      float t = (V[s][e] - mu) * rstd * g[e] + be[e];
      V[s][e] = 0.5f * t * (1.f + erff(t * 0.70710678118654752f));
    }
  }

#pragma unroll
  for (int i = 0; i < SGS; ++i) {
#pragma unroll
    for (int j = 0; j < SGS; ++j) {
      if (j < i) {
        float cc = 0.f, dd = 0.f;
#pragma unroll
        for (int e = 0; e < 16; ++e) { cc += V[i][e] * V[j][e]; dd += V[j][e] * V[j][e]; }
#pragma unroll
        for (int o = 1; o < 64; o <<= 1) { cc += __shfl_xor(cc, o); dd += __shfl_xor(dd, o); }
        const float proj = (sqrtf(dd) > EPS) ? cc / dd : 0.f;
#pragma unroll
        for (int e = 0; e < 16; ++e) V[i][e] -= proj * V[j][e];
      }
    }
    float nn = 0.f;
#pragma unroll
    for (int e = 0; e < 16; ++e) nn += V[i][e] * V[i][e];
#pragma unroll
    for (int o = 1; o < 64; o <<= 1) nn += __shfl_xor(nn, o);
    const float n = sqrtf(nn);
    if (n > EPS) {   // fallback branch statistically unreachable here
      const float inv = 1.f / n;
#pragma unroll
      for (int e = 0; e < 16; ++e) V[i][e] *= inv;
    }
  }

  unsigned short* hr = Hb + b * (i64)(SGS * H) + l * 16;
#pragma unroll
  for (int s = 0; s < SGS; ++s) {
    short8 o;
#pragma unroll
    for (int e = 0; e < 8; ++e) o[e] = (short)f2bf(V[s][e]);
    *(short8*)(void*)(hr + (i64)s * H) = o;
#pragma unroll
    for (int e = 0; e < 8; ++e) o[e] = (short)f2bf(V[s][8 + e]);
    *(short8*)(void*)(hr + (i64)s * H + 8) = o;
  }
}

__device__ __forceinline__ float block_red(float v, float* scr) {
#pragma unroll
  for (int o = 32; o; o >>= 1) v += __shfl_down(v, o);
  int w = threadIdx.x >> 6;
  if ((threadIdx.x & 63) == 0) scr[w] = v;
  __syncthreads();
  v = scr[0] + scr[1] + scr[2] + scr[3];
  __syncthreads();
  return v;
}

// --------- loss: sum((p-h)^2), p bf16, h bf16 ------------------------------
__global__ __launch_bounds__(256) void loss_part_k(
    const unsigned short* __restrict__ p, const unsigned short* __restrict__ hb,
    float* __restrict__ part)  // part pre-offset by chunk row0
{
  __shared__ float scr[8];
  const i64 b = blockIdx.x;
  const int s = blockIdx.y;
  const i64 base = b * (i64)(SGS * H) + (i64)s * H;
  const int e = threadIdx.x * 4;
  ushort4 pv = *(const ushort4*)(p + base + e);
  ushort4 hv = *(const ushort4*)(hb + base + e);
  float d0 = b2f(pv.x) - b2f(hv.x), d1 = b2f(pv.y) - b2f(hv.y);
  float d2 = b2f(pv.z) - b2f(hv.z), d3 = b2f(pv.w) - b2f(hv.w);
  float acc = d0 * d0 + d1 * d1 + d2 * d2 + d3 * d3;
  acc = block_red(acc, scr);
  if (threadIdx.x == 0) part[(i64)s * BATCH + b] = acc;
}

__global__ __launch_bounds__(256) void loss_red_k(
    const float* __restrict__ part, float* __restrict__ losses)
{
  __shared__ float scr[8];
  const int s = blockIdx.x;
  float acc = 0.f;
  for (int e = threadIdx.x; e < BATCH; e += 256) acc += part[(i64)s * BATCH + e];
  acc = block_red(acc, scr);
  if (threadIdx.x == 0) losses[s] = acc / (float)((i64)BATCH * H);
}

__global__ void finalize_k(const float* __restrict__ losses,
                           const float* __restrict__ w, float* __restrict__ o)
{
  if (threadIdx.x == 0) {
    float t = 0.f;
#pragma unroll
    for (int s = 0; s < SGS; ++s) { float l = losses[s]; o[1 + s] = l; t += w[s] * l; }
    o[0] = t;
  }
}

// ---------------------------------------------------------------------------
extern "C" void kernel_launch(void* const* d_in, const int* in_sizes, int n_in,
                              void* d_out, int out_size, void* d_ws, size_t ws_size,
                              hipStream_t stream)
{
  (void)in_sizes; (void)n_in; (void)out_size;
  const float* sent    = (const float*)d_in[0];
  const float* decompW = (const float*)d_in[1];
  const float* ln_g    = (const float*)d_in[2];
  const float* ln_b    = (const float*)d_in[3];
  const float* pw1     = (const float*)d_in[4];
  const float* pb1     = (const float*)d_in[5];
  const float* pw2     = (const float*)d_in[6];
  const float* pb2     = (const float*)d_in[7];
  const float* qw1     = (const float*)d_in[8];
  const float* qb1     = (const float*)d_in[9];
  const float* qw2     = (const float*)d_in[10];
  const float* qb2     = (const float*)d_in[11];
  const float* fw1     = (const float*)d_in[12];
  const float* fb1     = (const float*)d_in[13];
  const float* fw2     = (const float*)d_in[14];
  const float* fb2     = (const float*)d_in[15];
  const float* semw    = (const float*)d_in[16];
  float* out = (float*)d_out;

  float* ws = (float*)d_ws;
  const dim3 blk(256);
  const i64 HH = (i64)H * H;
  const i64 SH = (i64)SGS * H;
  const i64 SLABf = (i64)BATCH * SGS * H / 2;      // 14,680,064 fl per bf16 slab

  // full tier needs 3 slabs + W slab + part: 47,738,912 floats = 190.96 MB
  const bool full = ws_size >= (size_t)(3 * SLABf + 3670016 + 28704) * 4;

  if (full) {
    unsigned short* U1 = (unsigned short*)ws;                   // X->H; later fw1t/fw2t/T
    unsigned short* U2 = (unsigned short*)(ws + SLABf);         // z1 / p1
    unsigned short* Pb = (unsigned short*)(ws + 2 * SLABf);     // decompWt -> z2 -> p
    unsigned short* W  = (unsigned short*)(ws + 3 * SLABf);     // [7][1024][1024]
    float* part   = ws + 3 * SLABf + 3670016;                   // [7][4096]
    float* losses = part + (i64)SGS * BATCH;
    unsigned short* decompWt = Pb;                              // dies before z2
    unsigned short* fw1t = U1;                                  // after H dies
    unsigned short* fw2t = U1 + (i64)2 * H * SGS * H;           // +14,680,064 sh
    unsigned short* T    = fw2t + (i64)H * 2 * H;               // +2,097,152 sh

    // 1) decompWt; X = sent @ decompWt -> U1 (full batch, 1792 blocks)
    wtrans_k<<<dim3(224, 32, 1), blk, 0, stream>>>(decompW, decompWt, H, SGS * H, 0, 0);
    ggemm_k<0, 2><<<dim3(56, BATCH / 128, 1), blk, 0, stream>>>(
        sent, H, 0, decompWt, H, 0, nullptr, U1, SGS * H, 0, nullptr, 0, H, 0);
    // 2) H = MGS(gelu(LN(X))) in place
    lnmgs_k<<<dim3(BATCH / 4), blk, 0, stream>>>(U1, ln_g, ln_b, U1);
    // 3) SPR stages, full batch (1792 blocks each), one wtrans per weight
    wtrans_k<<<dim3(32, 32, SGS), blk, 0, stream>>>(pw1, W, H, H, HH, HH);
    ggemm_k<1, 2><<<dim3(8, BATCH / 128, SGS), blk, 0, stream>>>(
        U1, SH, H, W, H, HH, nullptr, U2, SH, H, pb1, H, H, 1);
    wtrans_k<<<dim3(32, 32, SGS), blk, 0, stream>>>(pw2, W, H, H, HH, HH);
    ggemm_k<1, 2><<<dim3(8, BATCH / 128, SGS), blk, 0, stream>>>(
        U2, SH, H, W, H, HH, nullptr, Pb, SH, H, pb2, H, H, 0);   // overwrites decompWt (dead)
    wtrans_k<<<dim3(32, 32, SGS), blk, 0, stream>>>(qw1, W, H, H, HH, HH);
    ggemm_k<1, 2><<<dim3(8, BATCH / 128, SGS), blk, 0, stream>>>(
        Pb, SH, H, W, H, HH, nullptr, U2, SH, H, qb1, H, H, 1);
    wtrans_k<<<dim3(32, 32, SGS), blk, 0, stream>>>(qw2, W, H, H, HH, HH);
    ggemm_k<1, 2><<<dim3(8, BATCH / 128, SGS), blk, 0, stream>>>(
        U2, SH, H, W, H, HH, nullptr, Pb, SH, H, qb2, H, H, 0);   // p -> Pb (z2 dead)
    // 4) loss (p in Pb vs H in U1)
    loss_part_k<<<dim3(BATCH, SGS), blk, 0, stream>>>(Pb, U1, part);
    // 5) fusion: H dead -> fw1t/fw2t/T into U1
    wtrans_k<<<dim3(64, 224, 1), blk, 0, stream>>>(fw1, fw1t, SGS * H, 2 * H, 0, 0);
    wtrans_k<<<dim3(32, 64, 1), blk, 0, stream>>>(fw2, fw2t, 2 * H, H, 0, 0);
    ggemm_k<1, 2><<<dim3(16, BATCH / 128, 1), blk, 0, stream>>>(
        Pb, SH, 0, fw1t, SGS * H, 0, nullptr, T, 2 * H, 0, fb1, 0, SGS * H, 1);
    ggemm_k<1, 1><<<dim3(8, BATCH / 128, 1), blk, 0, stream>>>(
        T, 2 * H, 0, fw2t, 2 * H, 0, out, nullptr, H, 0, fb2, 0, 2 * H, 0);
    loss_red_k<<<dim3(SGS), blk, 0, stream>>>(part, losses);
    finalize_k<<<dim3(1), dim3(64), 0, stream>>>(losses, semw, out + (i64)BATCH * H);
    return;
  }

  // -------- fallback: proven R7 layout (180.47MB), now with swizzle --------
  const int BC = 2048;
  unsigned short* W        = (unsigned short*)(ws);             // [7][1024][1024] (reused)
  unsigned short* decompWt = (unsigned short*)(ws + 3670016);   // [7168][1024]
  unsigned short* fw1t     = (unsigned short*)(ws + 7340032);   // [2048][7168]
  unsigned short* fw2t     = (unsigned short*)(ws + 14680064);  // [1024][2048]
  unsigned short* XH       = (unsigned short*)(ws + 15728640);  // chunk [2048][7168]
  unsigned short* Y        = (unsigned short*)(ws + 23068672);  // chunk [2048][7168]
  unsigned short* Pb       = (unsigned short*)(ws + 30408704);  // FULL [4096][7168]
  float* part   = ws + 45088768;                                // [7][4096]
  float* losses = part + (i64)SGS * BATCH;
  unsigned short* T = Y;

  wtrans_k<<<dim3(224, 32, 1), blk, 0, stream>>>(decompW, decompWt, H, SGS * H, 0, 0);
  wtrans_k<<<dim3(64, 224, 1), blk, 0, stream>>>(fw1, fw1t, SGS * H, 2 * H, 0, 0);
  wtrans_k<<<dim3(32, 64, 1), blk, 0, stream>>>(fw2, fw2t, 2 * H, H, 0, 0);

  for (int c = 0; c < BATCH / BC; ++c) {
    const i64 r0 = (i64)c * BC;
    unsigned short* Pc = Pb + r0 * SH;
    ggemm_k<0, 2><<<dim3(56, BC / 128, 1), blk, 0, stream>>>(
        sent + r0 * H, H, 0, decompWt, H, 0, nullptr, XH, SGS * H, 0,
        nullptr, 0, H, 0);
    lnmgs_k<<<dim3(BC / 4), blk, 0, stream>>>(XH, ln_g, ln_b, XH);
    wtrans_k<<<dim3(32, 32, SGS), blk, 0, stream>>>(pw1, W, H, H, HH, HH);
    ggemm_k<1, 2><<<dim3(8, BC / 128, SGS), blk, 0, stream>>>(
        XH, SH, H, W, H, HH, nullptr, Y, SH, H, pb1, H, H, 1);
    wtrans_k<<<dim3(32, 32, SGS), blk, 0, stream>>>(pw2, W, H, H, HH, HH);
    ggemm_k<1, 2><<<dim3(8, BC / 128, SGS), blk, 0, stream>>>(
        Y, SH, H, W, H, HH, nullptr, Pc, SH, H, pb2, H, H, 0);
    wtrans_k<<<dim3(32, 32, SGS), blk, 0, stream>>>(qw1, W, H, H, HH, HH);
    ggemm_k<1, 2><<<dim3(8, BC / 128, SGS), blk, 0, stream>>>(
        Pc, SH, H, W, H, HH, nullptr, Y, SH, H, qb1, H, H, 1);
    wtrans_k<<<dim3(32, 32, SGS), blk, 0, stream>>>(qw2, W, H, H, HH, HH);
    ggemm_k<1, 2><<<dim3(8, BC / 128, SGS), blk, 0, stream>>>(
        Y, SH, H, W, H, HH, nullptr, Pc, SH, H, qb2, H, H, 0);
    loss_part_k<<<dim3(BC, SGS), blk, 0, stream>>>(Pc, XH, part + r0);
  }

  ggemm_k<1, 2><<<dim3(16, BATCH / 128, 1), blk, 0, stream>>>(
      Pb, SH, 0, fw1t, SGS * H, 0, nullptr, T, 2 * H, 0, fb1, 0, SGS * H, 1);
  ggemm_k<1, 1><<<dim3(8, BATCH / 128, 1), blk, 0, stream>>>(
      T, 2 * H, 0, fw2t, 2 * H, 0, out, nullptr, H, 0, fb2, 0, 2 * H, 0);

  loss_red_k<<<dim3(SGS), blk, 0, stream>>>(part, losses);
  finalize_k<<<dim3(1), dim3(64), 0, stream>>>(losses, semw, out + (i64)BATCH * H);
}

// Round 10
// 1013.957 us; speedup vs baseline: 1.5192x; 1.0720x over previous
//
#include <hip/hip_runtime.h>
#include <hip/hip_bf16.h>

// MultiSemanticSPR: B=4096, H=1024, S=7
// Round 9: lnmgs_k rewrite (was 269us = 25% of runtime, latency-bound:
// 35 dependent shfl chains, 204 VGPR -> 2 waves/SIMD).
//  - All 7 LN reductions in ONE interleaved shfl chain (14-way ILP).
//  - Classical-GS dot batching: row i's projections onto orthonormal q_j
//    computed in one i-way-interleaved chain (== reference MGS to ~1e-6,
//    since q's are orthonormal); dd_j = nn*inv^2 scalar (no reduce).
//  - gamma/beta reloaded from L1 per use (frees 32 VGPR).
// GEMMs/swizzle/tiers identical to R8.

#define H 1024
#define SGS 7
#define BATCH 4096
#define EPS 1e-6f

typedef long long i64;
typedef __attribute__((ext_vector_type(8))) short short8;
typedef __attribute__((ext_vector_type(4))) float f32x4;

__device__ __forceinline__ unsigned short f2bf(float f) {
  __hip_bfloat16 h = __float2bfloat16(f);   // RNE
  return __builtin_bit_cast(unsigned short, h);
}
__device__ __forceinline__ float b2f(unsigned short u) {
  unsigned int x = ((unsigned int)u) << 16;
  return __builtin_bit_cast(float, x);
}
__device__ __forceinline__ short8 pack8(float4 a, float4 b) {
  short8 r;
  r[0] = (short)f2bf(a.x); r[1] = (short)f2bf(a.y);
  r[2] = (short)f2bf(a.z); r[3] = (short)f2bf(a.w);
  r[4] = (short)f2bf(b.x); r[5] = (short)f2bf(b.y);
  r[6] = (short)f2bf(b.z); r[7] = (short)f2bf(b.w);
  return r;
}

#define GL16(gp, lp)                                                        \
  __builtin_amdgcn_global_load_lds(                                         \
      (const __attribute__((address_space(1))) unsigned int*)(gp),          \
      (__attribute__((address_space(3))) unsigned int*)(lp), 16, 0, 0)

// Bijective XCD swizzle (m204): XCD (= orig%8) gets a contiguous chunk of
// the decoded index space; x decoded fastest so same-A-panel blocks cluster.
__device__ __forceinline__ void xcd_swz(int& bx, int& by, int& bz) {
  const int gx = gridDim.x, gy = gridDim.y;
  const int nwg = gx * gy * (int)gridDim.z;
  const int orig = blockIdx.x + gx * (blockIdx.y + gy * blockIdx.z);
  const int q = nwg >> 3, r = nwg & 7;
  const int xcd = orig & 7, idx = orig >> 3;
  const int nw = (xcd < r ? xcd * (q + 1) : r * (q + 1) + (xcd - r) * q) + idx;
  bx = nw % gx;
  const int t = nw / gx;
  by = t % gy;
  bz = t / gy;
}

// ============ m97-style GEMM: A[M][K] @ Bt[N][K]^T (+bias)(+relu) ==========
// A bf16 (ABF16=1, global_load_lds) or fp32 (ABF16=0, reg-staged); Bt bf16
// N-major. OM bit0 fp32 out, bit1 bf16 out. Tile 128x128, BK=32, 256 thr
// (4 waves, 64x64/wave, 4x4 frags of 16x16x32). LDS [128][32] bf16 linear,
// 16B slots XOR-swizzled both-sides (pre-swizzled global source).
template <int ABF16, int OM>
__global__ __launch_bounds__(256) void ggemm_k(
    const void* __restrict__ Av, int lda, i64 sA,
    const unsigned short* __restrict__ Bt, int ldb, i64 sB,
    float* __restrict__ Cf, unsigned short* __restrict__ Cb, int ldc, i64 sC,
    const float* __restrict__ bias, i64 sBias, int K, int relu)
{
  __shared__ __align__(16) unsigned short As[128 * 32];
  __shared__ __align__(16) unsigned short Bs[128 * 32];

  int bx, by, bz;
  xcd_swz(bx, by, bz);

  const int tid  = threadIdx.x;
  const int lane = tid & 63;
  const int w    = tid >> 6;
  const int wr   = w >> 1, wc = w & 1;   // wave tile rows wr*64, cols wc*64

  const i64 row0 = (i64)by * 128;
  const i64 col0 = (i64)bx * 128;

  const float* Af = (const float*)Av + (i64)bz * sA;
  const unsigned short* Ab = (const unsigned short*)Av + (i64)bz * sA;
  Bt += (i64)bz * sB;
  if (OM & 1) Cf += (i64)bz * sC;
  if (OM & 2) Cb += (i64)bz * sC;
  const float* bi = bias ? bias + (i64)bz * sBias : nullptr;

  // gload staging: wave w stages 32 LDS rows (2 calls x 16 rows); lane ->
  // row gr, 16B slot (l&3), global k-slot pre-swizzled gsl = (l&3)^(gr&3)
  const int gr  = lane >> 2;
  const int gsl = (lane & 3) ^ (gr & 3);
  const i64 aRow0 = row0 + w * 32 + gr;
  const i64 bRow0 = col0 + w * 32 + gr;
  const unsigned short* ApB = Ab + aRow0 * (i64)lda + gsl * 8;
  const unsigned short* BpB = Bt + bRow0 * (i64)ldb + gsl * 8;
  unsigned short* AlB = &As[(w * 32) * 32];
  unsigned short* BlB = &Bs[(w * 32) * 32];

  // fp32-A staging: thread t -> row t>>1, 16 k at (t&1)*16 (2 swizzled slots)
  const int arow = tid >> 1, aks = (tid & 1) * 2;
  const float* ApF = Af + (row0 + arow) * (i64)lda + aks * 8;

  f32x4 acc[4][4];
#pragma unroll
  for (int i = 0; i < 4; ++i)
#pragma unroll
    for (int j = 0; j < 4; ++j) acc[i][j] = (f32x4){0.f, 0.f, 0.f, 0.f};

  const int kq = lane >> 4, lr = lane & 15;

  for (int k0 = 0; k0 < K; k0 += 32) {
    float4 fa0, fa1, fa2, fa3;
    if constexpr (!ABF16) {   // load before barrier (overlaps prev MFMA)
      fa0 = *(const float4*)(ApF + k0);
      fa1 = *(const float4*)(ApF + k0 + 4);
      fa2 = *(const float4*)(ApF + k0 + 8);
      fa3 = *(const float4*)(ApF + k0 + 12);
    }
    __syncthreads();  // prior frag reads done before overwrite
    if constexpr (ABF16) {
      GL16(ApB + k0, AlB);
      GL16(ApB + k0 + (i64)16 * lda, AlB + 16 * 32);
    } else {
      *(short8*)(void*)&As[arow * 32 + (((aks)     ^ (arow & 3)) << 3)] = pack8(fa0, fa1);
      *(short8*)(void*)&As[arow * 32 + (((aks + 1) ^ (arow & 3)) << 3)] = pack8(fa2, fa3);
    }
    GL16(BpB + k0, BlB);
    GL16(BpB + k0 + (i64)16 * ldb, BlB + 16 * 32);
    __syncthreads();  // compiler drains vmcnt/lgkm before barrier

    short8 af[4], bf[4];
#pragma unroll
    for (int mf = 0; mf < 4; ++mf) {
      const int R = wr * 64 + mf * 16 + lr;
      af[mf] = *(const short8*)(const void*)&As[R * 32 + ((kq ^ (lr & 3)) << 3)];
    }
#pragma unroll
    for (int nf = 0; nf < 4; ++nf) {
      const int R = wc * 64 + nf * 16 + lr;
      bf[nf] = *(const short8*)(const void*)&Bs[R * 32 + ((kq ^ (lr & 3)) << 3)];
    }
#pragma unroll
    for (int mf = 0; mf < 4; ++mf)
#pragma unroll
      for (int nf = 0; nf < 4; ++nf)
        acc[mf][nf] = __builtin_amdgcn_mfma_f32_16x16x32_bf16(
            af[mf], bf[nf], acc[mf][nf], 0, 0, 0);
  }

  // epilogue: D col = lane&15, row = (lane>>4)*4 + reg  [verified r2-r8]
  const int cl = lane & 15, rg = lane >> 4;
#pragma unroll
  for (int nf = 0; nf < 4; ++nf) {
    const i64 col = col0 + wc * 64 + nf * 16 + cl;
    const float bv = bi ? bi[col] : 0.f;
#pragma unroll
    for (int mf = 0; mf < 4; ++mf) {
#pragma unroll
      for (int r = 0; r < 4; ++r) {
        const i64 row = row0 + wr * 64 + mf * 16 + rg * 4 + r;
        float v = acc[mf][nf][r] + bv;
        if (relu) v = fmaxf(v, 0.f);
        if (OM & 1) Cf[row * (i64)ldc + col] = v;
        if (OM & 2) Cb[row * (i64)ldc + col] = f2bf(v);
      }
    }
  }
}

// ---------- weight transpose+convert: in[K][N] fp32 -> out[N][K] bf16 ------
__global__ __launch_bounds__(256) void wtrans_k(
    const float* __restrict__ in, unsigned short* __restrict__ out,
    int Kd, int Nd, i64 sIn, i64 sOut)
{
  __shared__ float t[32][33];
  in  += (i64)blockIdx.z * sIn;
  out += (i64)blockIdx.z * sOut;
  const int n0 = blockIdx.x * 32, k0 = blockIdx.y * 32;
  const int tx = threadIdx.x & 31, ty = threadIdx.x >> 5;
#pragma unroll
  for (int i = 0; i < 4; ++i)
    t[ty + 8 * i][tx] = in[(i64)(k0 + ty + 8 * i) * Nd + n0 + tx];
  __syncthreads();
#pragma unroll
  for (int i = 0; i < 4; ++i)
    out[(i64)(n0 + ty + 8 * i) * Kd + k0 + tx] = f2bf(t[tx][ty + 8 * i]);
}

// ---------- fused LayerNorm + exact GELU + orthonorm: one WAVE per row -----
// LN: all 7 reductions in one interleaved shfl chain. Orthonorm: classical-GS
// dot batching (i-way ILP per chain); dd_j = nn*inv^2 (scalar, == dot(q,q)
// to ~1e-7). In-place safe: wave owns its row block.
__global__ __launch_bounds__(256) void lnmgs_k(
    const unsigned short* __restrict__ X, const float* __restrict__ gamma,
    const float* __restrict__ beta, unsigned short* __restrict__ Hb)
{
  const int wv = threadIdx.x >> 6, l = threadIdx.x & 63;
  const i64 b = (i64)blockIdx.x * 4 + wv;
  const unsigned short* xr = X + b * (i64)(SGS * H);

  float V[SGS][16];
  float s1[SGS], s2[SGS];
#pragma unroll
  for (int s = 0; s < SGS; ++s) {
#pragma unroll
    for (int q = 0; q < 2; ++q) {
      short8 v8 = *(const short8*)(const void*)(xr + (i64)s * H + l * 16 + q * 8);
#pragma unroll
      for (int e = 0; e < 8; ++e) V[s][q * 8 + e] = b2f((unsigned short)v8[e]);
    }
    s1[s] = 0.f; s2[s] = 0.f;
#pragma unroll
    for (int e = 0; e < 16; ++e) { s1[s] += V[s][e]; s2[s] += V[s][e] * V[s][e]; }
  }
  // one 6-step chain, 14 values interleaved (ILP hides bpermute latency)
#pragma unroll
  for (int o = 1; o < 64; o <<= 1) {
#pragma unroll
    for (int s = 0; s < SGS; ++s) {
      s1[s] += __shfl_xor(s1[s], o);
      s2[s] += __shfl_xor(s2[s], o);
    }
  }
  // LN + exact GELU (gamma/beta from L1 each use; frees 32 VGPR)
#pragma unroll
  for (int s = 0; s < SGS; ++s) {
    const float mu = s1[s] * (1.f / H);
    const float var = s2[s] * (1.f / H) - mu * mu;
    const float rstd = rsqrtf(var + 1e-5f);
#pragma unroll
    for (int q = 0; q < 4; ++q) {
      float4 gv = *(const float4*)(gamma + l * 16 + q * 4);
      float4 bv = *(const float4*)(beta + l * 16 + q * 4);
#pragma unroll
      for (int e = 0; e < 4; ++e) {
        float t = (V[s][q * 4 + e] - mu) * rstd * ((const float*)&gv)[e]
                  + ((const float*)&bv)[e];
        V[s][q * 4 + e] = 0.5f * t * (1.f + erff(t * 0.70710678118654752f));
      }
    }
  }

  // orthonormalization: CGS dot-batched (== reference MGS: q's orthonormal)
  float dd[SGS];
#pragma unroll
  for (int i = 0; i < SGS; ++i) {
    if (i > 0) {
      float cc[SGS > 1 ? SGS - 1 : 1];
#pragma unroll
      for (int j = 0; j < i; ++j) {
        cc[j] = 0.f;
#pragma unroll
        for (int e = 0; e < 16; ++e) cc[j] += V[i][e] * V[j][e];
      }
#pragma unroll
      for (int o = 1; o < 64; o <<= 1)
#pragma unroll
        for (int j = 0; j < i; ++j) cc[j] += __shfl_xor(cc[j], o);
#pragma unroll
      for (int j = 0; j < i; ++j) {
        const float proj = (sqrtf(dd[j]) > EPS) ? cc[j] / dd[j] : 0.f;
#pragma unroll
        for (int e = 0; e < 16; ++e) V[i][e] -= proj * V[j][e];
      }
    }
    float nn = 0.f;
#pragma unroll
    for (int e = 0; e < 16; ++e) nn += V[i][e] * V[i][e];
#pragma unroll
    for (int o = 1; o < 64; o <<= 1) nn += __shfl_xor(nn, o);
    const float n = sqrtf(nn);
    if (n > EPS) {   // fallback branch statistically unreachable here
      const float inv = 1.f / n;
#pragma unroll
      for (int e = 0; e < 16; ++e) V[i][e] *= inv;
      dd[i] = nn * inv * inv;    // == dot(q_i,q_i) to ~1e-7
    } else {
      dd[i] = 1.f;
    }
  }

  unsigned short* hr = Hb + b * (i64)(SGS * H) + l * 16;
#pragma unroll
  for (int s = 0; s < SGS; ++s) {
    short8 o;
#pragma unroll
    for (int e = 0; e < 8; ++e) o[e] = (short)f2bf(V[s][e]);
    *(short8*)(void*)(hr + (i64)s * H) = o;
#pragma unroll
    for (int e = 0; e < 8; ++e) o[e] = (short)f2bf(V[s][8 + e]);
    *(short8*)(void*)(hr + (i64)s * H + 8) = o;
  }
}

__device__ __forceinline__ float block_red(float v, float* scr) {
#pragma unroll
  for (int o = 32; o; o >>= 1) v += __shfl_down(v, o);
  int w = threadIdx.x >> 6;
  if ((threadIdx.x & 63) == 0) scr[w] = v;
  __syncthreads();
  v = scr[0] + scr[1] + scr[2] + scr[3];
  __syncthreads();
  return v;
}

// --------- loss: sum((p-h)^2), p bf16, h bf16 ------------------------------
__global__ __launch_bounds__(256) void loss_part_k(
    const unsigned short* __restrict__ p, const unsigned short* __restrict__ hb,
    float* __restrict__ part)  // part pre-offset by chunk row0
{
  __shared__ float scr[8];
  const i64 b = blockIdx.x;
  const int s = blockIdx.y;
  const i64 base = b * (i64)(SGS * H) + (i64)s * H;
  const int e = threadIdx.x * 4;
  ushort4 pv = *(const ushort4*)(p + base + e);
  ushort4 hv = *(const ushort4*)(hb + base + e);
  float d0 = b2f(pv.x) - b2f(hv.x), d1 = b2f(pv.y) - b2f(hv.y);
  float d2 = b2f(pv.z) - b2f(hv.z), d3 = b2f(pv.w) - b2f(hv.w);
  float acc = d0 * d0 + d1 * d1 + d2 * d2 + d3 * d3;
  acc = block_red(acc, scr);
  if (threadIdx.x == 0) part[(i64)s * BATCH + b] = acc;
}

__global__ __launch_bounds__(256) void loss_red_k(
    const float* __restrict__ part, float* __restrict__ losses)
{
  __shared__ float scr[8];
  const int s = blockIdx.x;
  float acc = 0.f;
  for (int e = threadIdx.x; e < BATCH; e += 256) acc += part[(i64)s * BATCH + e];
  acc = block_red(acc, scr);
  if (threadIdx.x == 0) losses[s] = acc / (float)((i64)BATCH * H);
}

__global__ void finalize_k(const float* __restrict__ losses,
                           const float* __restrict__ w, float* __restrict__ o)
{
  if (threadIdx.x == 0) {
    float t = 0.f;
#pragma unroll
    for (int s = 0; s < SGS; ++s) { float l = losses[s]; o[1 + s] = l; t += w[s] * l; }
    o[0] = t;
  }
}

// ---------------------------------------------------------------------------
extern "C" void kernel_launch(void* const* d_in, const int* in_sizes, int n_in,
                              void* d_out, int out_size, void* d_ws, size_t ws_size,
                              hipStream_t stream)
{
  (void)in_sizes; (void)n_in; (void)out_size;
  const float* sent    = (const float*)d_in[0];
  const float* decompW = (const float*)d_in[1];
  const float* ln_g    = (const float*)d_in[2];
  const float* ln_b    = (const float*)d_in[3];
  const float* pw1     = (const float*)d_in[4];
  const float* pb1     = (const float*)d_in[5];
  const float* pw2     = (const float*)d_in[6];
  const float* pb2     = (const float*)d_in[7];
  const float* qw1     = (const float*)d_in[8];
  const float* qb1     = (const float*)d_in[9];
  const float* qw2     = (const float*)d_in[10];
  const float* qb2     = (const float*)d_in[11];
  const float* fw1     = (const float*)d_in[12];
  const float* fb1     = (const float*)d_in[13];
  const float* fw2     = (const float*)d_in[14];
  const float* fb2     = (const float*)d_in[15];
  const float* semw    = (const float*)d_in[16];
  float* out = (float*)d_out;

  float* ws = (float*)d_ws;
  const dim3 blk(256);
  const i64 HH = (i64)H * H;
  const i64 SH = (i64)SGS * H;
  const i64 SLABf = (i64)BATCH * SGS * H / 2;      // 14,680,064 fl per bf16 slab

  // full tier needs 3 slabs + W slab + part: 47,738,912 floats = 190.96 MB
  const bool full = ws_size >= (size_t)(3 * SLABf + 3670016 + 28704) * 4;

  if (full) {
    unsigned short* U1 = (unsigned short*)ws;                   // X->H; later fw1t/fw2t/T
    unsigned short* U2 = (unsigned short*)(ws + SLABf);         // z1 / p1
    unsigned short* Pb = (unsigned short*)(ws + 2 * SLABf);     // decompWt -> z2 -> p
    unsigned short* W  = (unsigned short*)(ws + 3 * SLABf);     // [7][1024][1024]
    float* part   = ws + 3 * SLABf + 3670016;                   // [7][4096]
    float* losses = part + (i64)SGS * BATCH;
    unsigned short* decompWt = Pb;                              // dies before z2
    unsigned short* fw1t = U1;                                  // after H dies
    unsigned short* fw2t = U1 + (i64)2 * H * SGS * H;           // +14,680,064 sh
    unsigned short* T    = fw2t + (i64)H * 2 * H;               // +2,097,152 sh

    // 1) decompWt; X = sent @ decompWt -> U1 (full batch, 1792 blocks)
    wtrans_k<<<dim3(224, 32, 1), blk, 0, stream>>>(decompW, decompWt, H, SGS * H, 0, 0);
    ggemm_k<0, 2><<<dim3(56, BATCH / 128, 1), blk, 0, stream>>>(
        sent, H, 0, decompWt, H, 0, nullptr, U1, SGS * H, 0, nullptr, 0, H, 0);
    // 2) H = orthonorm(gelu(LN(X))) in place
    lnmgs_k<<<dim3(BATCH / 4), blk, 0, stream>>>(U1, ln_g, ln_b, U1);
    // 3) SPR stages, full batch (1792 blocks each), one wtrans per weight
    wtrans_k<<<dim3(32, 32, SGS), blk, 0, stream>>>(pw1, W, H, H, HH, HH);
    ggemm_k<1, 2><<<dim3(8, BATCH / 128, SGS), blk, 0, stream>>>(
        U1, SH, H, W, H, HH, nullptr, U2, SH, H, pb1, H, H, 1);
    wtrans_k<<<dim3(32, 32, SGS), blk, 0, stream>>>(pw2, W, H, H, HH, HH);
    ggemm_k<1, 2><<<dim3(8, BATCH / 128, SGS), blk, 0, stream>>>(
        U2, SH, H, W, H, HH, nullptr, Pb, SH, H, pb2, H, H, 0);   // overwrites decompWt (dead)
    wtrans_k<<<dim3(32, 32, SGS), blk, 0, stream>>>(qw1, W, H, H, HH, HH);
    ggemm_k<1, 2><<<dim3(8, BATCH / 128, SGS), blk, 0, stream>>>(
        Pb, SH, H, W, H, HH, nullptr, U2, SH, H, qb1, H, H, 1);
    wtrans_k<<<dim3(32, 32, SGS), blk, 0, stream>>>(qw2, W, H, H, HH, HH);
    ggemm_k<1, 2><<<dim3(8, BATCH / 128, SGS), blk, 0, stream>>>(
        U2, SH, H, W, H, HH, nullptr, Pb, SH, H, qb2, H, H, 0);   // p -> Pb (z2 dead)
    // 4) loss (p in Pb vs H in U1)
    loss_part_k<<<dim3(BATCH, SGS), blk, 0, stream>>>(Pb, U1, part);
    // 5) fusion: H dead -> fw1t/fw2t/T into U1
    wtrans_k<<<dim3(64, 224, 1), blk, 0, stream>>>(fw1, fw1t, SGS * H, 2 * H, 0, 0);
    wtrans_k<<<dim3(32, 64, 1), blk, 0, stream>>>(fw2, fw2t, 2 * H, H, 0, 0);
    ggemm_k<1, 2><<<dim3(16, BATCH / 128, 1), blk, 0, stream>>>(
        Pb, SH, 0, fw1t, SGS * H, 0, nullptr, T, 2 * H, 0, fb1, 0, SGS * H, 1);
    ggemm_k<1, 1><<<dim3(8, BATCH / 128, 1), blk, 0, stream>>>(
        T, 2 * H, 0, fw2t, 2 * H, 0, out, nullptr, H, 0, fb2, 0, 2 * H, 0);
    loss_red_k<<<dim3(SGS), blk, 0, stream>>>(part, losses);
    finalize_k<<<dim3(1), dim3(64), 0, stream>>>(losses, semw, out + (i64)BATCH * H);
    return;
  }

  // -------- fallback: proven R7 layout (180.47MB), swizzled --------
  const int BC = 2048;
  unsigned short* W        = (unsigned short*)(ws);             // [7][1024][1024] (reused)
  unsigned short* decompWt = (unsigned short*)(ws + 3670016);   // [7168][1024]
  unsigned short* fw1t     = (unsigned short*)(ws + 7340032);   // [2048][7168]
  unsigned short* fw2t     = (unsigned short*)(ws + 14680064);  // [1024][2048]
  unsigned short* XH       = (unsigned short*)(ws + 15728640);  // chunk [2048][7168]
  unsigned short* Y        = (unsigned short*)(ws + 23068672);  // chunk [2048][7168]
  unsigned short* Pb       = (unsigned short*)(ws + 30408704);  // FULL [4096][7168]
  float* part   = ws + 45088768;                                // [7][4096]
  float* losses = part + (i64)SGS * BATCH;
  unsigned short* T = Y;

  wtrans_k<<<dim3(224, 32, 1), blk, 0, stream>>>(decompW, decompWt, H, SGS * H, 0, 0);
  wtrans_k<<<dim3(64, 224, 1), blk, 0, stream>>>(fw1, fw1t, SGS * H, 2 * H, 0, 0);
  wtrans_k<<<dim3(32, 64, 1), blk, 0, stream>>>(fw2, fw2t, 2 * H, H, 0, 0);

  for (int c = 0; c < BATCH / BC; ++c) {
    const i64 r0 = (i64)c * BC;
    unsigned short* Pc = Pb + r0 * SH;
    ggemm_k<0, 2><<<dim3(56, BC / 128, 1), blk, 0, stream>>>(
        sent + r0 * H, H, 0, decompWt, H, 0, nullptr, XH, SGS * H, 0,
        nullptr, 0, H, 0);
    lnmgs_k<<<dim3(BC / 4), blk, 0, stream>>>(XH, ln_g, ln_b, XH);
    wtrans_k<<<dim3(32, 32, SGS), blk, 0, stream>>>(pw1, W, H, H, HH, HH);
    ggemm_k<1, 2><<<dim3(8, BC / 128, SGS), blk, 0, stream>>>(
        XH, SH, H, W, H, HH, nullptr, Y, SH, H, pb1, H, H, 1);
    wtrans_k<<<dim3(32, 32, SGS), blk, 0, stream>>>(pw2, W, H, H, HH, HH);
    ggemm_k<1, 2><<<dim3(8, BC / 128, SGS), blk, 0, stream>>>(
        Y, SH, H, W, H, HH, nullptr, Pc, SH, H, pb2, H, H, 0);
    wtrans_k<<<dim3(32, 32, SGS), blk, 0, stream>>>(qw1, W, H, H, HH, HH);
    ggemm_k<1, 2><<<dim3(8, BC / 128, SGS), blk, 0, stream>>>(
        Pc, SH, H, W, H, HH, nullptr, Y, SH, H, qb1, H, H, 1);
    wtrans_k<<<dim3(32, 32, SGS), blk, 0, stream>>>(qw2, W, H, H, HH, HH);
    ggemm_k<1, 2><<<dim3(8, BC / 128, SGS), blk, 0, stream>>>(
        Y, SH, H, W, H, HH, nullptr, Pc, SH, H, qb2, H, H, 0);
    loss_part_k<<<dim3(BC, SGS), blk, 0, stream>>>(Pc, XH, part + r0);
  }

  ggemm_k<1, 2><<<dim3(16, BATCH / 128, 1), blk, 0, stream>>>(
      Pb, SH, 0, fw1t, SGS * H, 0, nullptr, T, 2 * H, 0, fb1, 0, SGS * H, 1);
  ggemm_k<1, 1><<<dim3(8, BATCH / 128, 1), blk, 0, stream>>>(
      T, 2 * H, 0, fw2t, 2 * H, 0, out, nullptr, H, 0, fb2, 0, 2 * H, 0);

  loss_red_k<<<dim3(SGS), blk, 0, stream>>>(part, losses);
  finalize_k<<<dim3(1), dim3(64), 0, stream>>>(losses, semw, out + (i64)BATCH * H);
}